// Round 16
// baseline (322.234 us; speedup 1.0000x reference)
//
#include <hip/hip_runtime.h>
#include <stdint.h>

#define NN 512
#define PP (NN * NN)   // 262144 positions

typedef __attribute__((ext_vector_type(8))) short bf16x8;
typedef __attribute__((ext_vector_type(4))) float f32x4;

#define MFMA16 __builtin_amdgcn_mfma_f32_16x16x32_bf16

__device__ __forceinline__ unsigned short f2bf(float f) {
  unsigned u = __float_as_uint(f);
  u += 0x7fffu + ((u >> 16) & 1u);   // round-to-nearest-even
  return (unsigned short)(u >> 16);
}
__device__ __forceinline__ float bf2f(unsigned short s) {
  return __uint_as_float(((unsigned)s) << 16);
}
__device__ __forceinline__ unsigned pack2(float a, float b) {
  return (unsigned)f2bf(a) | ((unsigned)f2bf(b) << 16);
}
__device__ __forceinline__ float sigm(float t) { return 1.0f / (1.0f + __expf(-t)); }

// swizzled LDS index for [p][h] tiles, row stride 136 ushorts (272B).
// XOR of p bits 3-5 into h bits 3-5; keeps 8-aligned h-chunks 16B-aligned.
__device__ __forceinline__ int sidx(int p, int h) {
  return p * 136 + (h ^ (((p >> 3) & 7) << 3));
}

// ---------------- K0: transpose + cast the 6 128x128 weights to bf16 -------
__global__ __launch_bounds__(256) void k_prep(
    const float* __restrict__ w0, const float* __restrict__ w1,
    const float* __restrict__ w2, const float* __restrict__ w3,
    const float* __restrict__ w4, const float* __restrict__ w5,
    unsigned short* __restrict__ outw) {
  const float* src;
  switch (blockIdx.x) {
    case 0: src = w0; break; case 1: src = w1; break; case 2: src = w2; break;
    case 3: src = w3; break; case 4: src = w4; break; default: src = w5; break;
  }
  unsigned short* o = outw + blockIdx.x * 16384;
  for (int idx = threadIdx.x; idx < 16384; idx += 256) {
    int r = idx >> 7, c = idx & 127;
    o[idx] = f2bf(src[c * 128 + r]);
  }
}

// ---------------- K1: LayerNorm over D=128, fp32 in -> bf16 out ------------
__global__ __launch_bounds__(256) void k_ln(
    const float* __restrict__ x, const float* __restrict__ g,
    const float* __restrict__ b, unsigned short* __restrict__ xn) {
  const int lane = threadIdx.x & 63, wid = threadIdx.x >> 6;
  const int row = blockIdx.x * 32 + wid * 8 + (lane >> 3);
  const int ch = lane & 7;
  const float4* xr = (const float4*)(x + (size_t)row * 128 + ch * 16);
  float4 V[4];
  float s = 0.f, ss = 0.f;
#pragma unroll
  for (int q = 0; q < 4; ++q) {
    V[q] = xr[q];
    s  += V[q].x + V[q].y + V[q].z + V[q].w;
    ss += V[q].x * V[q].x + V[q].y * V[q].y + V[q].z * V[q].z + V[q].w * V[q].w;
  }
#pragma unroll
  for (int o = 1; o < 8; o <<= 1) { s += __shfl_xor(s, o); ss += __shfl_xor(ss, o); }
  float mu  = s * 0.0078125f;
  float var = ss * 0.0078125f - mu * mu;
  float rs  = rsqrtf(var + 1e-5f);
  const float4* gp = (const float4*)(g + ch * 16);
  const float4* bp = (const float4*)(b + ch * 16);
  unsigned pk[8];
#pragma unroll
  for (int q = 0; q < 4; ++q) {
    float4 vv = V[q], gg = gp[q], bb = bp[q];
    pk[2 * q]     = pack2((vv.x - mu) * rs * gg.x + bb.x, (vv.y - mu) * rs * gg.y + bb.y);
    pk[2 * q + 1] = pack2((vv.z - mu) * rs * gg.z + bb.z, (vv.w - mu) * rs * gg.w + bb.w);
  }
  unsigned short* dst = xn + (size_t)row * 128 + ch * 16;
  *(uint4*)dst       = make_uint4(pk[0], pk[1], pk[2], pk[3]);
  *(uint4*)(dst + 8) = make_uint4(pk[4], pk[5], pk[6], pk[7]);
}

// ---------------- K2/K3: masked+gated projection ---------------------------
// v3: sW eliminated.  Weight A-fragments read straight from global (32KB
// L2-resident broadcast matrices; same rows in every block), exactly like
// k_final's GEMM1 (VGPR-104 precedent, 2 GEMMs only -> no R12 hoist blowup).
// LDS = sX only (34.8KB -> 4 blocks/CU = 16 waves, 2x current), ONE barrier.
__global__ __launch_bounds__(256) void k_proj(
    const unsigned short* __restrict__ xn,
    const unsigned short* __restrict__ WpT, const float* __restrict__ bp,
    const unsigned short* __restrict__ WgT, const float* __restrict__ bg,
    const int* __restrict__ mask,
    unsigned short* __restrict__ outb) {
  const int c  = blockIdx.y;
  const int k0 = blockIdx.x * 128;
  const int t = threadIdx.x, lane = t & 63, wid = t >> 6;
  const int wm = (wid >> 1) * 64, wn = (wid & 1) * 64;
  const int lr = lane & 15, lg = lane >> 4;
  __shared__ unsigned short sX[128 * 136];   // [k-local][d], padded rows

#pragma unroll
  for (int it = 0; it < 8; ++it) {
    int lin = it * 256 + t;
    int r = lin >> 4, ch = lin & 15;
    *(uint4*)&sX[r * 136 + ch * 8] =
        *(const uint4*)&xn[((size_t)(k0 + r) * NN + c) * 128 + ch * 8];
  }

  const int maskc = mask[c];
  float mcol[4];
#pragma unroll
  for (int n = 0; n < 4; ++n)
    mcol[n] = (float)(maskc * mask[k0 + wn + n * 16 + lr]);

  __syncthreads();                           // the only barrier

  f32x4 acc[4][4];
#pragma unroll
  for (int m = 0; m < 4; ++m)
#pragma unroll
    for (int n = 0; n < 4; ++n) { acc[m][n][0] = 0.f; acc[m][n][1] = 0.f; acc[m][n][2] = 0.f; acc[m][n][3] = 0.f; }

  // ---- gate GEMM: av = WgT fragments from global, bv = sX from LDS
#pragma unroll
  for (int kk = 0; kk < 4; ++kk) {
    bf16x8 av[4], bv[4];
#pragma unroll
    for (int m = 0; m < 4; ++m)
      av[m] = *(const bf16x8*)&WgT[(wm + m * 16 + lr) * 128 + kk * 32 + lg * 8];
#pragma unroll
    for (int n = 0; n < 4; ++n)
      bv[n] = *(const bf16x8*)&sX[(wn + n * 16 + lr) * 136 + kk * 32 + lg * 8];
#pragma unroll
    for (int m = 0; m < 4; ++m)
#pragma unroll
      for (int n = 0; n < 4; ++n)
        acc[m][n] = MFMA16(av[m], bv[n], acc[m][n], 0, 0, 0);
  }
  float sg[4][4][4];
#pragma unroll
  for (int m = 0; m < 4; ++m)
#pragma unroll
    for (int r = 0; r < 4; ++r) {
      int h = wm + m * 16 + lg * 4 + r;
      float bgv = bg[h];
#pragma unroll
      for (int n = 0; n < 4; ++n) sg[m][n][r] = sigm(acc[m][n][r] + bgv);
    }

  // ---- proj GEMM: av = WpT fragments from global, bv = sX from LDS
#pragma unroll
  for (int m = 0; m < 4; ++m)
#pragma unroll
    for (int n = 0; n < 4; ++n) { acc[m][n][0] = 0.f; acc[m][n][1] = 0.f; acc[m][n][2] = 0.f; acc[m][n][3] = 0.f; }
#pragma unroll
  for (int kk = 0; kk < 4; ++kk) {
    bf16x8 av[4], bv[4];
#pragma unroll
    for (int m = 0; m < 4; ++m)
      av[m] = *(const bf16x8*)&WpT[(wm + m * 16 + lr) * 128 + kk * 32 + lg * 8];
#pragma unroll
    for (int n = 0; n < 4; ++n)
      bv[n] = *(const bf16x8*)&sX[(wn + n * 16 + lr) * 136 + kk * 32 + lg * 8];
#pragma unroll
    for (int m = 0; m < 4; ++m)
#pragma unroll
      for (int n = 0; n < 4; ++n)
        acc[m][n] = MFMA16(av[m], bv[n], acc[m][n], 0, 0, 0);
  }

#pragma unroll
  for (int m = 0; m < 4; ++m)
#pragma unroll
    for (int r = 0; r < 4; ++r) {
      int h = wm + m * 16 + lg * 4 + r;
      float bpv = bp[h];
#pragma unroll
      for (int n = 0; n < 4; ++n) {
        float v = (acc[m][n][r] + bpv) * mcol[n] * sg[m][n][r];
        outb[(size_t)h * PP + (size_t)c * NN + k0 + wn + n * 16 + lr] = f2bf(v);
      }
    }
}

// ---------------- K4: einsum bkjd,bkid->bijd as 128 batched 512^3 GEMMs ----
// 256x256 tile per block, 512 threads = 8 waves (2x4), each 128x64.
// T14 async-STAGE prefetch: kb+1's global loads issued before kb's compute.
__global__ __launch_bounds__(512) void k_einsum(
    const unsigned short* __restrict__ rightT,
    const unsigned short* __restrict__ leftT,
    unsigned short* __restrict__ tmp) {
  const int bid = (blockIdx.x & 7) * 64 + (blockIdx.x >> 3);  // 512 = 8*64
  const int d = bid >> 2;
  const int i0 = ((bid >> 1) & 1) * 256, j0 = (bid & 1) * 256;
  const unsigned short* A = rightT + (size_t)d * PP;
  const unsigned short* B = leftT + (size_t)d * PP;
  const int t = threadIdx.x, lane = t & 63, wid = t >> 6;
  const int wm = (wid >> 2) * 128, wn = (wid & 3) * 64;
  const int lr = lane & 15, lg = lane >> 4;
  const int sr = t >> 3;                     // staging row 0..63 (+64*it)
  const int sc = (t & 7) * 8;                // staging col elem (16B chunks)
  __shared__ unsigned short sA[256 * 72];    // [i-local][k-local], padded
  __shared__ unsigned short sB[256 * 72];    // [j-local][k-local]

  f32x4 acc[8][4];
#pragma unroll
  for (int m = 0; m < 8; ++m)
#pragma unroll
    for (int n = 0; n < 4; ++n) { acc[m][n][0] = 0.f; acc[m][n][1] = 0.f; acc[m][n][2] = 0.f; acc[m][n][3] = 0.f; }

  // prologue: stage kb=0 directly
  uint4 pa0, pa1, pa2, pa3, pb0, pb1, pb2, pb3;
  pa0 = *(const uint4*)&A[(size_t)(i0 + sr)       * NN + sc];
  pa1 = *(const uint4*)&A[(size_t)(i0 + 64 + sr)  * NN + sc];
  pa2 = *(const uint4*)&A[(size_t)(i0 + 128 + sr) * NN + sc];
  pa3 = *(const uint4*)&A[(size_t)(i0 + 192 + sr) * NN + sc];
  pb0 = *(const uint4*)&B[(size_t)(j0 + sr)       * NN + sc];
  pb1 = *(const uint4*)&B[(size_t)(j0 + 64 + sr)  * NN + sc];
  pb2 = *(const uint4*)&B[(size_t)(j0 + 128 + sr) * NN + sc];
  pb3 = *(const uint4*)&B[(size_t)(j0 + 192 + sr) * NN + sc];
  *(uint4*)&sA[(sr)       * 72 + sc] = pa0;
  *(uint4*)&sA[(64 + sr)  * 72 + sc] = pa1;
  *(uint4*)&sA[(128 + sr) * 72 + sc] = pa2;
  *(uint4*)&sA[(192 + sr) * 72 + sc] = pa3;
  *(uint4*)&sB[(sr)       * 72 + sc] = pb0;
  *(uint4*)&sB[(64 + sr)  * 72 + sc] = pb1;
  *(uint4*)&sB[(128 + sr) * 72 + sc] = pb2;
  *(uint4*)&sB[(192 + sr) * 72 + sc] = pb3;
  __syncthreads();

  for (int kb = 0; kb < 8; ++kb) {
    if (kb < 7) {                            // issue kb+1 loads (in flight
      const int ko = (kb + 1) * 64 + sc;     //  across the compute below)
      pa0 = *(const uint4*)&A[(size_t)(i0 + sr)       * NN + ko];
      pa1 = *(const uint4*)&A[(size_t)(i0 + 64 + sr)  * NN + ko];
      pa2 = *(const uint4*)&A[(size_t)(i0 + 128 + sr) * NN + ko];
      pa3 = *(const uint4*)&A[(size_t)(i0 + 192 + sr) * NN + ko];
      pb0 = *(const uint4*)&B[(size_t)(j0 + sr)       * NN + ko];
      pb1 = *(const uint4*)&B[(size_t)(j0 + 64 + sr)  * NN + ko];
      pb2 = *(const uint4*)&B[(size_t)(j0 + 128 + sr) * NN + ko];
      pb3 = *(const uint4*)&B[(size_t)(j0 + 192 + sr) * NN + ko];
    }
#pragma unroll
    for (int kk = 0; kk < 2; ++kk) {
      bf16x8 bv[4];
#pragma unroll
      for (int n = 0; n < 4; ++n)
        bv[n] = *(const bf16x8*)&sB[(wn + n * 16 + lr) * 72 + kk * 32 + lg * 8];
#pragma unroll
      for (int m = 0; m < 8; ++m) {
        bf16x8 av = *(const bf16x8*)&sA[(wm + m * 16 + lr) * 72 + kk * 32 + lg * 8];
#pragma unroll
        for (int n = 0; n < 4; ++n)
          acc[m][n] = MFMA16(av, bv[n], acc[m][n], 0, 0, 0);
      }
    }
    __syncthreads();                         // everyone done reading kb
    if (kb < 7) {
      *(uint4*)&sA[(sr)       * 72 + sc] = pa0;
      *(uint4*)&sA[(64 + sr)  * 72 + sc] = pa1;
      *(uint4*)&sA[(128 + sr) * 72 + sc] = pa2;
      *(uint4*)&sA[(192 + sr) * 72 + sc] = pa3;
      *(uint4*)&sB[(sr)       * 72 + sc] = pb0;
      *(uint4*)&sB[(64 + sr)  * 72 + sc] = pb1;
      *(uint4*)&sB[(128 + sr) * 72 + sc] = pb2;
      *(uint4*)&sB[(192 + sr) * 72 + sc] = pb3;
    }
    __syncthreads();                         // kb+1 visible
  }

#pragma unroll
  for (int m = 0; m < 8; ++m)
#pragma unroll
    for (int r = 0; r < 4; ++r) {
      int row = wm + m * 16 + lg * 4 + r;
#pragma unroll
      for (int n = 0; n < 4; ++n) {
        int col = wn + n * 16 + lr;
        tmp[(size_t)d * PP + (size_t)(i0 + row) * NN + j0 + col] = f2bf(acc[m][n][r]);
      }
    }
}

// ---------------- K5: out-LN * sigmoid(xn@Wog+bog), @Wo + bo ---------------
// v3 (best measured: ~92us; floor of this structure per R10 falsification).
__global__ __launch_bounds__(256, 2) void k_final(
    const unsigned short* __restrict__ xn,
    const unsigned short* __restrict__ WogT, const float* __restrict__ bog,
    const unsigned short* __restrict__ WoT, const float* __restrict__ bo,
    const unsigned short* __restrict__ tmp,
    const float* __restrict__ og, const float* __restrict__ ob,
    float* __restrict__ out) {
  const int p0 = blockIdx.x * 128;
  const int t = threadIdx.x, lane = t & 63, wid = t >> 6;
  const int wm = (wid >> 1) * 64, wn = (wid & 1) * 64;
  const int lr = lane & 15, lg = lane >> 4;
  __shared__ unsigned short sT[128 * 136];   // tmp tile, [p][h] swizzled
  __shared__ unsigned short sSig[128 * 136]; // sigmoid gate, [p][h] swizzled
  __shared__ float muL[128], rsL[128];

  // ---- stage sT: per thread 8 coalesced u32 loads (2p x 8h) -> 2x b128
  {
    const int pb = 2 * lane;
#pragma unroll
    for (int q = 0; q < 4; ++q) {
      int h0 = (q * 4 + wid) * 8;
      unsigned a[8];
#pragma unroll
      for (int e = 0; e < 8; ++e)
        a[e] = *(const unsigned*)&tmp[(size_t)(h0 + e) * PP + p0 + pb];
      bf16x8 y0, y1;
#pragma unroll
      for (int e = 0; e < 8; ++e) {
        y0[e] = (short)(a[e] & 0xffffu);
        y1[e] = (short)(a[e] >> 16);
      }
      *(bf16x8*)&sT[sidx(pb, h0)]     = y0;
      *(bf16x8*)&sT[sidx(pb + 1, h0)] = y1;
    }
  }

  // ---- GEMM1: sig pre-activation C[p,h] = xn @ Wog (fragments from global)
  f32x4 acc[4][4];
#pragma unroll
  for (int m = 0; m < 4; ++m)
#pragma unroll
    for (int n = 0; n < 4; ++n) { acc[m][n][0] = 0.f; acc[m][n][1] = 0.f; acc[m][n][2] = 0.f; acc[m][n][3] = 0.f; }
#pragma unroll
  for (int kk = 0; kk < 4; ++kk) {
    bf16x8 av[4], bv[4];
#pragma unroll
    for (int m = 0; m < 4; ++m)
      av[m] = *(const bf16x8*)&xn[(size_t)(p0 + wm + m * 16 + lr) * 128 + kk * 32 + lg * 8];
#pragma unroll
    for (int n = 0; n < 4; ++n)
      bv[n] = *(const bf16x8*)&WogT[(wn + n * 16 + lr) * 128 + kk * 32 + lg * 8];
#pragma unroll
    for (int m = 0; m < 4; ++m)
#pragma unroll
      for (int n = 0; n < 4; ++n)
        acc[m][n] = MFMA16(av[m], bv[n], acc[m][n], 0, 0, 0);
  }
  float bogv[4];
#pragma unroll
  for (int n = 0; n < 4; ++n) bogv[n] = bog[wn + n * 16 + lr];
#pragma unroll
  for (int m = 0; m < 4; ++m)
#pragma unroll
    for (int r = 0; r < 4; ++r) {
      int p = wm + m * 16 + lg * 4 + r;
#pragma unroll
      for (int n = 0; n < 4; ++n)
        sSig[sidx(p, wn + n * 16 + lr)] = f2bf(sigm(acc[m][n][r] + bogv[n]));
    }
  __syncthreads();

  // ---- LN stats from sT: 2 threads per row
  {
    int p = t >> 1, half = t & 1;
    float s = 0.f, ss = 0.f;
#pragma unroll
    for (int c = 0; c < 8; ++c) {
      bf16x8 v = *(const bf16x8*)&sT[sidx(p, half * 64 + c * 8)];
#pragma unroll
      for (int e = 0; e < 8; ++e) {
        float f = bf2f((unsigned short)v[e]);
        s += f; ss += f * f;
      }
    }
    s += __shfl_xor(s, 1); ss += __shfl_xor(ss, 1);
    if (half == 0) {
      float mu = s * 0.0078125f;
      float var = ss * 0.0078125f - mu * mu;
      muL[p] = mu;
      rsL[p] = rsqrtf(var + 1e-5f);
    }
  }
  __syncthreads();

  // ---- GEMM2: out[p,e] = y @ Wo, y built on the fly from sT/sSig/LN
#pragma unroll
  for (int m = 0; m < 4; ++m)
#pragma unroll
    for (int n = 0; n < 4; ++n) { acc[m][n][0] = 0.f; acc[m][n][1] = 0.f; acc[m][n][2] = 0.f; acc[m][n][3] = 0.f; }
  float muR[4], rsR[4];
#pragma unroll
  for (int m = 0; m < 4; ++m) {
    int p = wm + m * 16 + lr;
    muR[m] = muL[p]; rsR[m] = rsL[p];
  }
#pragma unroll
  for (int kk = 0; kk < 4; ++kk) {
    const int h0 = kk * 32 + lg * 8;
    float ogv[8], obv[8];
    *(float4*)&ogv[0] = *(const float4*)&og[h0];
    *(float4*)&ogv[4] = *(const float4*)&og[h0 + 4];
    *(float4*)&obv[0] = *(const float4*)&ob[h0];
    *(float4*)&obv[4] = *(const float4*)&ob[h0 + 4];
    bf16x8 av[4], bv[4];
#pragma unroll
    for (int m = 0; m < 4; ++m) {
      int p = wm + m * 16 + lr;
      float mu = muR[m], rr = rsR[m];
      bf16x8 tv = *(const bf16x8*)&sT[sidx(p, h0)];
      bf16x8 gv = *(const bf16x8*)&sSig[sidx(p, h0)];
      bf16x8 y;
#pragma unroll
      for (int e = 0; e < 8; ++e) {
        float tf = bf2f((unsigned short)tv[e]);
        float yf = ((tf - mu) * rr * ogv[e] + obv[e]) * bf2f((unsigned short)gv[e]);
        y[e] = (short)f2bf(yf);
      }
      av[m] = y;
    }
#pragma unroll
    for (int n = 0; n < 4; ++n)
      bv[n] = *(const bf16x8*)&WoT[(wn + n * 16 + lr) * 128 + h0];
#pragma unroll
    for (int m = 0; m < 4; ++m)
#pragma unroll
      for (int n = 0; n < 4; ++n)
        acc[m][n] = MFMA16(av[m], bv[n], acc[m][n], 0, 0, 0);
  }

  float bov[4];
#pragma unroll
  for (int n = 0; n < 4; ++n) bov[n] = bo[wn + n * 16 + lr];
#pragma unroll
  for (int m = 0; m < 4; ++m)
#pragma unroll
    for (int r = 0; r < 4; ++r) {
      int p = wm + m * 16 + lg * 4 + r;
#pragma unroll
      for (int n = 0; n < 4; ++n)
        out[(size_t)(p0 + p) * 128 + wn + n * 16 + lr] = acc[m][n][r] + bov[n];
    }
}

extern "C" void kernel_launch(void* const* d_in, const int* in_sizes, int n_in,
                              void* d_out, int out_size, void* d_ws, size_t ws_size,
                              hipStream_t stream) {
  (void)in_sizes; (void)n_in; (void)out_size;
  const float* x    = (const float*)d_in[0];
  const int*   msk  = (const int*)d_in[1];
  const float* ln_g = (const float*)d_in[2];
  const float* ln_b = (const float*)d_in[3];
  const float* Wl   = (const float*)d_in[4];
  const float* bl   = (const float*)d_in[5];
  const float* Wr   = (const float*)d_in[6];
  const float* br   = (const float*)d_in[7];
  const float* Wlg  = (const float*)d_in[8];
  const float* blg  = (const float*)d_in[9];
  const float* Wrg  = (const float*)d_in[10];
  const float* brg  = (const float*)d_in[11];
  const float* Wog  = (const float*)d_in[12];
  const float* bog  = (const float*)d_in[13];
  const float* olng = (const float*)d_in[14];
  const float* olnb = (const float*)d_in[15];
  const float* Wo   = (const float*)d_in[16];
  const float* bo   = (const float*)d_in[17];
  float* out = (float*)d_out;

  const size_t need = (1ull << 20) + 4ull * (1ull << 26);
  if (ws_size < need) return;
  char* ws = (char*)d_ws;
  unsigned short* wT    = (unsigned short*)ws;
  unsigned short* xn    = (unsigned short*)(ws + (1ull << 20));
  unsigned short* leftT = (unsigned short*)(ws + (1ull << 20) + (1ull << 26));
  unsigned short* rightT= (unsigned short*)(ws + (1ull << 20) + (2ull << 26));
  unsigned short* tmp   = (unsigned short*)(ws + (1ull << 20) + (3ull << 26));

  hipLaunchKernelGGL(k_prep, dim3(6), dim3(256), 0, stream, Wl, Wr, Wlg, Wrg, Wog, Wo, wT);
  hipLaunchKernelGGL(k_ln, dim3(PP / 32), dim3(256), 0, stream, x, ln_g, ln_b, xn);
  hipLaunchKernelGGL(k_proj, dim3(4, NN), dim3(256), 0, stream,
                     xn, wT + 0 * 16384, bl, wT + 2 * 16384, blg, msk, leftT);
  hipLaunchKernelGGL(k_proj, dim3(4, NN), dim3(256), 0, stream,
                     xn, wT + 1 * 16384, br, wT + 3 * 16384, brg, msk, rightT);
  hipLaunchKernelGGL(k_einsum, dim3(512), dim3(512), 0, stream, rightT, leftT, tmp);
  hipLaunchKernelGGL(k_final, dim3(PP / 128), dim3(256), 0, stream,
                     xn, wT + 4 * 16384, bog, wT + 5 * 16384, bo, tmp, olng, olnb, out);
}

// Round 17
// 270.066 us; speedup vs baseline: 1.1932x; 1.1932x over previous
//
#include <hip/hip_runtime.h>
#include <stdint.h>

#define NN 512
#define PP (NN * NN)   // 262144 positions

typedef __attribute__((ext_vector_type(8))) short bf16x8;
typedef __attribute__((ext_vector_type(4))) float f32x4;

#define MFMA16 __builtin_amdgcn_mfma_f32_16x16x32_bf16

__device__ __forceinline__ unsigned short f2bf(float f) {
  unsigned u = __float_as_uint(f);
  u += 0x7fffu + ((u >> 16) & 1u);   // round-to-nearest-even
  return (unsigned short)(u >> 16);
}
__device__ __forceinline__ float bf2f(unsigned short s) {
  return __uint_as_float(((unsigned)s) << 16);
}
__device__ __forceinline__ unsigned pack2(float a, float b) {
  return (unsigned)f2bf(a) | ((unsigned)f2bf(b) << 16);
}
__device__ __forceinline__ float sigm(float t) { return 1.0f / (1.0f + __expf(-t)); }

// swizzled LDS index for [p][h] tiles, row stride 136 ushorts (272B).
// XOR of p bits 3-5 into h bits 3-5; keeps 8-aligned h-chunks 16B-aligned.
__device__ __forceinline__ int sidx(int p, int h) {
  return p * 136 + (h ^ (((p >> 3) & 7) << 3));
}

// ---------------- K0: transpose + cast the 6 128x128 weights to bf16 -------
__global__ __launch_bounds__(256) void k_prep(
    const float* __restrict__ w0, const float* __restrict__ w1,
    const float* __restrict__ w2, const float* __restrict__ w3,
    const float* __restrict__ w4, const float* __restrict__ w5,
    unsigned short* __restrict__ outw) {
  const float* src;
  switch (blockIdx.x) {
    case 0: src = w0; break; case 1: src = w1; break; case 2: src = w2; break;
    case 3: src = w3; break; case 4: src = w4; break; default: src = w5; break;
  }
  unsigned short* o = outw + blockIdx.x * 16384;
  for (int idx = threadIdx.x; idx < 16384; idx += 256) {
    int r = idx >> 7, c = idx & 127;
    o[idx] = f2bf(src[c * 128 + r]);
  }
}

// ---------------- K1: LayerNorm over D=128, fp32 in -> bf16 out ------------
__global__ __launch_bounds__(256) void k_ln(
    const float* __restrict__ x, const float* __restrict__ g,
    const float* __restrict__ b, unsigned short* __restrict__ xn) {
  const int lane = threadIdx.x & 63, wid = threadIdx.x >> 6;
  const int row = blockIdx.x * 32 + wid * 8 + (lane >> 3);
  const int ch = lane & 7;
  const float4* xr = (const float4*)(x + (size_t)row * 128 + ch * 16);
  float4 V[4];
  float s = 0.f, ss = 0.f;
#pragma unroll
  for (int q = 0; q < 4; ++q) {
    V[q] = xr[q];
    s  += V[q].x + V[q].y + V[q].z + V[q].w;
    ss += V[q].x * V[q].x + V[q].y * V[q].y + V[q].z * V[q].z + V[q].w * V[q].w;
  }
#pragma unroll
  for (int o = 1; o < 8; o <<= 1) { s += __shfl_xor(s, o); ss += __shfl_xor(ss, o); }
  float mu  = s * 0.0078125f;
  float var = ss * 0.0078125f - mu * mu;
  float rs  = rsqrtf(var + 1e-5f);
  const float4* gp = (const float4*)(g + ch * 16);
  const float4* bp = (const float4*)(b + ch * 16);
  unsigned pk[8];
#pragma unroll
  for (int q = 0; q < 4; ++q) {
    float4 vv = V[q], gg = gp[q], bb = bp[q];
    pk[2 * q]     = pack2((vv.x - mu) * rs * gg.x + bb.x, (vv.y - mu) * rs * gg.y + bb.y);
    pk[2 * q + 1] = pack2((vv.z - mu) * rs * gg.z + bb.z, (vv.w - mu) * rs * gg.w + bb.w);
  }
  unsigned short* dst = xn + (size_t)row * 128 + ch * 16;
  *(uint4*)dst       = make_uint4(pk[0], pk[1], pk[2], pk[3]);
  *(uint4*)(dst + 8) = make_uint4(pk[4], pk[5], pk[6], pk[7]);
}

// ---------------- K2/K3: masked+gated projection ---------------------------
__global__ __launch_bounds__(256) void k_proj(
    const unsigned short* __restrict__ xn,
    const unsigned short* __restrict__ WpT, const float* __restrict__ bp,
    const unsigned short* __restrict__ WgT, const float* __restrict__ bg,
    const int* __restrict__ mask,
    unsigned short* __restrict__ outb) {
  const int c  = blockIdx.y;
  const int k0 = blockIdx.x * 128;
  const int t = threadIdx.x, lane = t & 63, wid = t >> 6;
  const int wm = (wid >> 1) * 64, wn = (wid & 1) * 64;
  const int lr = lane & 15, lg = lane >> 4;
  __shared__ unsigned short sX[128 * 136];   // [k-local][d], padded rows
  __shared__ unsigned short sW[128 * 136];   // [h][d]

#pragma unroll
  for (int it = 0; it < 8; ++it) {
    int lin = it * 256 + t;
    int r = lin >> 4, ch = lin & 15;
    *(uint4*)&sX[r * 136 + ch * 8] =
        *(const uint4*)&xn[((size_t)(k0 + r) * NN + c) * 128 + ch * 8];
  }
#pragma unroll
  for (int it = 0; it < 8; ++it) {
    int lin = it * 256 + t;
    *(uint4*)&sW[(lin >> 4) * 136 + (lin & 15) * 8] = *(const uint4*)&WgT[lin * 8];
  }
  __syncthreads();

  f32x4 acc[4][4];
#pragma unroll
  for (int m = 0; m < 4; ++m)
#pragma unroll
    for (int n = 0; n < 4; ++n) { acc[m][n][0] = 0.f; acc[m][n][1] = 0.f; acc[m][n][2] = 0.f; acc[m][n][3] = 0.f; }

#pragma unroll
  for (int kk = 0; kk < 4; ++kk) {
    bf16x8 av[4], bv[4];
#pragma unroll
    for (int m = 0; m < 4; ++m)
      av[m] = *(const bf16x8*)&sW[(wm + m * 16 + lr) * 136 + kk * 32 + lg * 8];
#pragma unroll
    for (int n = 0; n < 4; ++n)
      bv[n] = *(const bf16x8*)&sX[(wn + n * 16 + lr) * 136 + kk * 32 + lg * 8];
#pragma unroll
    for (int m = 0; m < 4; ++m)
#pragma unroll
      for (int n = 0; n < 4; ++n)
        acc[m][n] = MFMA16(av[m], bv[n], acc[m][n], 0, 0, 0);
  }
  float sg[4][4][4];
#pragma unroll
  for (int m = 0; m < 4; ++m)
#pragma unroll
    for (int r = 0; r < 4; ++r) {
      int h = wm + m * 16 + lg * 4 + r;
      float bgv = bg[h];
#pragma unroll
      for (int n = 0; n < 4; ++n) sg[m][n][r] = sigm(acc[m][n][r] + bgv);
    }
  __syncthreads();
#pragma unroll
  for (int it = 0; it < 8; ++it) {
    int lin = it * 256 + t;
    *(uint4*)&sW[(lin >> 4) * 136 + (lin & 15) * 8] = *(const uint4*)&WpT[lin * 8];
  }
  __syncthreads();

#pragma unroll
  for (int m = 0; m < 4; ++m)
#pragma unroll
    for (int n = 0; n < 4; ++n) { acc[m][n][0] = 0.f; acc[m][n][1] = 0.f; acc[m][n][2] = 0.f; acc[m][n][3] = 0.f; }
#pragma unroll
  for (int kk = 0; kk < 4; ++kk) {
    bf16x8 av[4], bv[4];
#pragma unroll
    for (int m = 0; m < 4; ++m)
      av[m] = *(const bf16x8*)&sW[(wm + m * 16 + lr) * 136 + kk * 32 + lg * 8];
#pragma unroll
    for (int n = 0; n < 4; ++n)
      bv[n] = *(const bf16x8*)&sX[(wn + n * 16 + lr) * 136 + kk * 32 + lg * 8];
#pragma unroll
    for (int m = 0; m < 4; ++m)
#pragma unroll
      for (int n = 0; n < 4; ++n)
        acc[m][n] = MFMA16(av[m], bv[n], acc[m][n], 0, 0, 0);
  }

  const int maskc = mask[c];
  float mcol[4];
#pragma unroll
  for (int n = 0; n < 4; ++n)
    mcol[n] = (float)(maskc * mask[k0 + wn + n * 16 + lr]);
#pragma unroll
  for (int m = 0; m < 4; ++m)
#pragma unroll
    for (int r = 0; r < 4; ++r) {
      int h = wm + m * 16 + lg * 4 + r;
      float bpv = bp[h];
#pragma unroll
      for (int n = 0; n < 4; ++n) {
        float v = (acc[m][n][r] + bpv) * mcol[n] * sg[m][n][r];
        outb[(size_t)h * PP + (size_t)c * NN + k0 + wn + n * 16 + lr] = f2bf(v);
      }
    }
}

// ---------------- K4: einsum bkjd,bkid->bijd as 128 batched 512^3 GEMMs ----
// 256x256 tile per block, 512 threads = 8 waves (2x4), each 128x64.
// T14 async-STAGE prefetch: kb+1's global loads issued before kb's compute.
__global__ __launch_bounds__(512) void k_einsum(
    const unsigned short* __restrict__ rightT,
    const unsigned short* __restrict__ leftT,
    unsigned short* __restrict__ tmp) {
  const int bid = (blockIdx.x & 7) * 64 + (blockIdx.x >> 3);  // 512 = 8*64
  const int d = bid >> 2;
  const int i0 = ((bid >> 1) & 1) * 256, j0 = (bid & 1) * 256;
  const unsigned short* A = rightT + (size_t)d * PP;
  const unsigned short* B = leftT + (size_t)d * PP;
  const int t = threadIdx.x, lane = t & 63, wid = t >> 6;
  const int wm = (wid >> 2) * 128, wn = (wid & 3) * 64;
  const int lr = lane & 15, lg = lane >> 4;
  const int sr = t >> 3;                     // staging row 0..63 (+64*it)
  const int sc = (t & 7) * 8;                // staging col elem (16B chunks)
  __shared__ unsigned short sA[256 * 72];    // [i-local][k-local], padded
  __shared__ unsigned short sB[256 * 72];    // [j-local][k-local]

  f32x4 acc[8][4];
#pragma unroll
  for (int m = 0; m < 8; ++m)
#pragma unroll
    for (int n = 0; n < 4; ++n) { acc[m][n][0] = 0.f; acc[m][n][1] = 0.f; acc[m][n][2] = 0.f; acc[m][n][3] = 0.f; }

  // prologue: stage kb=0 directly
  uint4 pa0, pa1, pa2, pa3, pb0, pb1, pb2, pb3;
  pa0 = *(const uint4*)&A[(size_t)(i0 + sr)       * NN + sc];
  pa1 = *(const uint4*)&A[(size_t)(i0 + 64 + sr)  * NN + sc];
  pa2 = *(const uint4*)&A[(size_t)(i0 + 128 + sr) * NN + sc];
  pa3 = *(const uint4*)&A[(size_t)(i0 + 192 + sr) * NN + sc];
  pb0 = *(const uint4*)&B[(size_t)(j0 + sr)       * NN + sc];
  pb1 = *(const uint4*)&B[(size_t)(j0 + 64 + sr)  * NN + sc];
  pb2 = *(const uint4*)&B[(size_t)(j0 + 128 + sr) * NN + sc];
  pb3 = *(const uint4*)&B[(size_t)(j0 + 192 + sr) * NN + sc];
  *(uint4*)&sA[(sr)       * 72 + sc] = pa0;
  *(uint4*)&sA[(64 + sr)  * 72 + sc] = pa1;
  *(uint4*)&sA[(128 + sr) * 72 + sc] = pa2;
  *(uint4*)&sA[(192 + sr) * 72 + sc] = pa3;
  *(uint4*)&sB[(sr)       * 72 + sc] = pb0;
  *(uint4*)&sB[(64 + sr)  * 72 + sc] = pb1;
  *(uint4*)&sB[(128 + sr) * 72 + sc] = pb2;
  *(uint4*)&sB[(192 + sr) * 72 + sc] = pb3;
  __syncthreads();

  for (int kb = 0; kb < 8; ++kb) {
    if (kb < 7) {                            // issue kb+1 loads (in flight
      const int ko = (kb + 1) * 64 + sc;     //  across the compute below)
      pa0 = *(const uint4*)&A[(size_t)(i0 + sr)       * NN + ko];
      pa1 = *(const uint4*)&A[(size_t)(i0 + 64 + sr)  * NN + ko];
      pa2 = *(const uint4*)&A[(size_t)(i0 + 128 + sr) * NN + ko];
      pa3 = *(const uint4*)&A[(size_t)(i0 + 192 + sr) * NN + ko];
      pb0 = *(const uint4*)&B[(size_t)(j0 + sr)       * NN + ko];
      pb1 = *(const uint4*)&B[(size_t)(j0 + 64 + sr)  * NN + ko];
      pb2 = *(const uint4*)&B[(size_t)(j0 + 128 + sr) * NN + ko];
      pb3 = *(const uint4*)&B[(size_t)(j0 + 192 + sr) * NN + ko];
    }
#pragma unroll
    for (int kk = 0; kk < 2; ++kk) {
      bf16x8 bv[4];
#pragma unroll
      for (int n = 0; n < 4; ++n)
        bv[n] = *(const bf16x8*)&sB[(wn + n * 16 + lr) * 72 + kk * 32 + lg * 8];
#pragma unroll
      for (int m = 0; m < 8; ++m) {
        bf16x8 av = *(const bf16x8*)&sA[(wm + m * 16 + lr) * 72 + kk * 32 + lg * 8];
#pragma unroll
        for (int n = 0; n < 4; ++n)
          acc[m][n] = MFMA16(av, bv[n], acc[m][n], 0, 0, 0);
      }
    }
    __syncthreads();                         // everyone done reading kb
    if (kb < 7) {
      *(uint4*)&sA[(sr)       * 72 + sc] = pa0;
      *(uint4*)&sA[(64 + sr)  * 72 + sc] = pa1;
      *(uint4*)&sA[(128 + sr) * 72 + sc] = pa2;
      *(uint4*)&sA[(192 + sr) * 72 + sc] = pa3;
      *(uint4*)&sB[(sr)       * 72 + sc] = pb0;
      *(uint4*)&sB[(64 + sr)  * 72 + sc] = pb1;
      *(uint4*)&sB[(128 + sr) * 72 + sc] = pb2;
      *(uint4*)&sB[(192 + sr) * 72 + sc] = pb3;
    }
    __syncthreads();                         // kb+1 visible
  }

#pragma unroll
  for (int m = 0; m < 8; ++m)
#pragma unroll
    for (int r = 0; r < 4; ++r) {
      int row = wm + m * 16 + lg * 4 + r;
#pragma unroll
      for (int n = 0; n < 4; ++n) {
        int col = wn + n * 16 + lr;
        tmp[(size_t)d * PP + (size_t)(i0 + row) * NN + j0 + col] = f2bf(acc[m][n][r]);
      }
    }
}

// ---------------- K5: out-LN * sigmoid(xn@Wog+bog), @Wo + bo ---------------
// v3 (best measured: ~92us; floor of this structure per R10 falsification).
__global__ __launch_bounds__(256, 2) void k_final(
    const unsigned short* __restrict__ xn,
    const unsigned short* __restrict__ WogT, const float* __restrict__ bog,
    const unsigned short* __restrict__ WoT, const float* __restrict__ bo,
    const unsigned short* __restrict__ tmp,
    const float* __restrict__ og, const float* __restrict__ ob,
    float* __restrict__ out) {
  const int p0 = blockIdx.x * 128;
  const int t = threadIdx.x, lane = t & 63, wid = t >> 6;
  const int wm = (wid >> 1) * 64, wn = (wid & 1) * 64;
  const int lr = lane & 15, lg = lane >> 4;
  __shared__ unsigned short sT[128 * 136];   // tmp tile, [p][h] swizzled
  __shared__ unsigned short sSig[128 * 136]; // sigmoid gate, [p][h] swizzled
  __shared__ float muL[128], rsL[128];

  // ---- stage sT: per thread 8 coalesced u32 loads (2p x 8h) -> 2x b128
  {
    const int pb = 2 * lane;
#pragma unroll
    for (int q = 0; q < 4; ++q) {
      int h0 = (q * 4 + wid) * 8;
      unsigned a[8];
#pragma unroll
      for (int e = 0; e < 8; ++e)
        a[e] = *(const unsigned*)&tmp[(size_t)(h0 + e) * PP + p0 + pb];
      bf16x8 y0, y1;
#pragma unroll
      for (int e = 0; e < 8; ++e) {
        y0[e] = (short)(a[e] & 0xffffu);
        y1[e] = (short)(a[e] >> 16);
      }
      *(bf16x8*)&sT[sidx(pb, h0)]     = y0;
      *(bf16x8*)&sT[sidx(pb + 1, h0)] = y1;
    }
  }

  // ---- GEMM1: sig pre-activation C[p,h] = xn @ Wog (fragments from global)
  f32x4 acc[4][4];
#pragma unroll
  for (int m = 0; m < 4; ++m)
#pragma unroll
    for (int n = 0; n < 4; ++n) { acc[m][n][0] = 0.f; acc[m][n][1] = 0.f; acc[m][n][2] = 0.f; acc[m][n][3] = 0.f; }
#pragma unroll
  for (int kk = 0; kk < 4; ++kk) {
    bf16x8 av[4], bv[4];
#pragma unroll
    for (int m = 0; m < 4; ++m)
      av[m] = *(const bf16x8*)&xn[(size_t)(p0 + wm + m * 16 + lr) * 128 + kk * 32 + lg * 8];
#pragma unroll
    for (int n = 0; n < 4; ++n)
      bv[n] = *(const bf16x8*)&WogT[(wn + n * 16 + lr) * 128 + kk * 32 + lg * 8];
#pragma unroll
    for (int m = 0; m < 4; ++m)
#pragma unroll
      for (int n = 0; n < 4; ++n)
        acc[m][n] = MFMA16(av[m], bv[n], acc[m][n], 0, 0, 0);
  }
  float bogv[4];
#pragma unroll
  for (int n = 0; n < 4; ++n) bogv[n] = bog[wn + n * 16 + lr];
#pragma unroll
  for (int m = 0; m < 4; ++m)
#pragma unroll
    for (int r = 0; r < 4; ++r) {
      int p = wm + m * 16 + lg * 4 + r;
#pragma unroll
      for (int n = 0; n < 4; ++n)
        sSig[sidx(p, wn + n * 16 + lr)] = f2bf(sigm(acc[m][n][r] + bogv[n]));
    }
  __syncthreads();

  // ---- LN stats from sT: 2 threads per row
  {
    int p = t >> 1, half = t & 1;
    float s = 0.f, ss = 0.f;
#pragma unroll
    for (int c = 0; c < 8; ++c) {
      bf16x8 v = *(const bf16x8*)&sT[sidx(p, half * 64 + c * 8)];
#pragma unroll
      for (int e = 0; e < 8; ++e) {
        float f = bf2f((unsigned short)v[e]);
        s += f; ss += f * f;
      }
    }
    s += __shfl_xor(s, 1); ss += __shfl_xor(ss, 1);
    if (half == 0) {
      float mu = s * 0.0078125f;
      float var = ss * 0.0078125f - mu * mu;
      muL[p] = mu;
      rsL[p] = rsqrtf(var + 1e-5f);
    }
  }
  __syncthreads();

  // ---- GEMM2: out[p,e] = y @ Wo, y built on the fly from sT/sSig/LN
#pragma unroll
  for (int m = 0; m < 4; ++m)
#pragma unroll
    for (int n = 0; n < 4; ++n) { acc[m][n][0] = 0.f; acc[m][n][1] = 0.f; acc[m][n][2] = 0.f; acc[m][n][3] = 0.f; }
  float muR[4], rsR[4];
#pragma unroll
  for (int m = 0; m < 4; ++m) {
    int p = wm + m * 16 + lr;
    muR[m] = muL[p]; rsR[m] = rsL[p];
  }
#pragma unroll
  for (int kk = 0; kk < 4; ++kk) {
    const int h0 = kk * 32 + lg * 8;
    float ogv[8], obv[8];
    *(float4*)&ogv[0] = *(const float4*)&og[h0];
    *(float4*)&ogv[4] = *(const float4*)&og[h0 + 4];
    *(float4*)&obv[0] = *(const float4*)&ob[h0];
    *(float4*)&obv[4] = *(const float4*)&ob[h0 + 4];
    bf16x8 av[4], bv[4];
#pragma unroll
    for (int m = 0; m < 4; ++m) {
      int p = wm + m * 16 + lr;
      float mu = muR[m], rr = rsR[m];
      bf16x8 tv = *(const bf16x8*)&sT[sidx(p, h0)];
      bf16x8 gv = *(const bf16x8*)&sSig[sidx(p, h0)];
      bf16x8 y;
#pragma unroll
      for (int e = 0; e < 8; ++e) {
        float tf = bf2f((unsigned short)tv[e]);
        float yf = ((tf - mu) * rr * ogv[e] + obv[e]) * bf2f((unsigned short)gv[e]);
        y[e] = (short)f2bf(yf);
      }
      av[m] = y;
    }
#pragma unroll
    for (int n = 0; n < 4; ++n)
      bv[n] = *(const bf16x8*)&WoT[(wn + n * 16 + lr) * 128 + h0];
#pragma unroll
    for (int m = 0; m < 4; ++m)
#pragma unroll
      for (int n = 0; n < 4; ++n)
        acc[m][n] = MFMA16(av[m], bv[n], acc[m][n], 0, 0, 0);
  }

  float bov[4];
#pragma unroll
  for (int n = 0; n < 4; ++n) bov[n] = bo[wn + n * 16 + lr];
#pragma unroll
  for (int m = 0; m < 4; ++m)
#pragma unroll
    for (int r = 0; r < 4; ++r) {
      int p = wm + m * 16 + lg * 4 + r;
#pragma unroll
      for (int n = 0; n < 4; ++n)
        out[(size_t)(p0 + p) * 128 + wn + n * 16 + lr] = acc[m][n][r] + bov[n];
    }
}

extern "C" void kernel_launch(void* const* d_in, const int* in_sizes, int n_in,
                              void* d_out, int out_size, void* d_ws, size_t ws_size,
                              hipStream_t stream) {
  (void)in_sizes; (void)n_in; (void)out_size;
  const float* x    = (const float*)d_in[0];
  const int*   msk  = (const int*)d_in[1];
  const float* ln_g = (const float*)d_in[2];
  const float* ln_b = (const float*)d_in[3];
  const float* Wl   = (const float*)d_in[4];
  const float* bl   = (const float*)d_in[5];
  const float* Wr   = (const float*)d_in[6];
  const float* br   = (const float*)d_in[7];
  const float* Wlg  = (const float*)d_in[8];
  const float* blg  = (const float*)d_in[9];
  const float* Wrg  = (const float*)d_in[10];
  const float* brg  = (const float*)d_in[11];
  const float* Wog  = (const float*)d_in[12];
  const float* bog  = (const float*)d_in[13];
  const float* olng = (const float*)d_in[14];
  const float* olnb = (const float*)d_in[15];
  const float* Wo   = (const float*)d_in[16];
  const float* bo   = (const float*)d_in[17];
  float* out = (float*)d_out;

  const size_t need = (1ull << 20) + 4ull * (1ull << 26);
  if (ws_size < need) return;
  char* ws = (char*)d_ws;
  unsigned short* wT    = (unsigned short*)ws;
  unsigned short* xn    = (unsigned short*)(ws + (1ull << 20));
  unsigned short* leftT = (unsigned short*)(ws + (1ull << 20) + (1ull << 26));
  unsigned short* rightT= (unsigned short*)(ws + (1ull << 20) + (2ull << 26));
  unsigned short* tmp   = (unsigned short*)(ws + (1ull << 20) + (3ull << 26));

  hipLaunchKernelGGL(k_prep, dim3(6), dim3(256), 0, stream, Wl, Wr, Wlg, Wrg, Wog, Wo, wT);
  hipLaunchKernelGGL(k_ln, dim3(PP / 32), dim3(256), 0, stream, x, ln_g, ln_b, xn);
  hipLaunchKernelGGL(k_proj, dim3(4, NN), dim3(256), 0, stream,
                     xn, wT + 0 * 16384, bl, wT + 2 * 16384, blg, msk, leftT);
  hipLaunchKernelGGL(k_proj, dim3(4, NN), dim3(256), 0, stream,
                     xn, wT + 1 * 16384, br, wT + 3 * 16384, brg, msk, rightT);
  hipLaunchKernelGGL(k_einsum, dim3(512), dim3(512), 0, stream, rightT, leftT, tmp);
  hipLaunchKernelGGL(k_final, dim3(PP / 128), dim3(256), 0, stream,
                     xn, wT + 4 * 16384, bog, wT + 5 * 16384, bo, tmp, olng, olnb, out);
}

// Round 18
// 262.802 us; speedup vs baseline: 1.2261x; 1.0276x over previous
//
#include <hip/hip_runtime.h>
#include <stdint.h>

#define NN 512
#define PP (NN * NN)   // 262144 positions

typedef __attribute__((ext_vector_type(8))) short bf16x8;
typedef __attribute__((ext_vector_type(4))) float f32x4;

#define MFMA16 __builtin_amdgcn_mfma_f32_16x16x32_bf16

__device__ __forceinline__ unsigned short f2bf(float f) {
  unsigned u = __float_as_uint(f);
  u += 0x7fffu + ((u >> 16) & 1u);   // round-to-nearest-even
  return (unsigned short)(u >> 16);
}
__device__ __forceinline__ float bf2f(unsigned short s) {
  return __uint_as_float(((unsigned)s) << 16);
}
__device__ __forceinline__ unsigned pack2(float a, float b) {
  return (unsigned)f2bf(a) | ((unsigned)f2bf(b) << 16);
}
__device__ __forceinline__ float sigm(float t) { return 1.0f / (1.0f + __expf(-t)); }

// swizzled LDS index for [p][h] tiles, row stride 136 ushorts (272B).
// XOR of p bits 3-5 into h bits 3-5; keeps 8-aligned h-chunks 16B-aligned.
__device__ __forceinline__ int sidx(int p, int h) {
  return p * 136 + (h ^ (((p >> 3) & 7) << 3));
}

// ---------------- K0: transpose + cast the 6 128x128 weights to bf16 -------
__global__ __launch_bounds__(256) void k_prep(
    const float* __restrict__ w0, const float* __restrict__ w1,
    const float* __restrict__ w2, const float* __restrict__ w3,
    const float* __restrict__ w4, const float* __restrict__ w5,
    unsigned short* __restrict__ outw) {
  const float* src;
  switch (blockIdx.x) {
    case 0: src = w0; break; case 1: src = w1; break; case 2: src = w2; break;
    case 3: src = w3; break; case 4: src = w4; break; default: src = w5; break;
  }
  unsigned short* o = outw + blockIdx.x * 16384;
  for (int idx = threadIdx.x; idx < 16384; idx += 256) {
    int r = idx >> 7, c = idx & 127;
    o[idx] = f2bf(src[c * 128 + r]);
  }
}

// ---------------- K1: LayerNorm over D=128, fp32 in -> bf16 out ------------
__global__ __launch_bounds__(256) void k_ln(
    const float* __restrict__ x, const float* __restrict__ g,
    const float* __restrict__ b, unsigned short* __restrict__ xn) {
  const int lane = threadIdx.x & 63, wid = threadIdx.x >> 6;
  const int row = blockIdx.x * 32 + wid * 8 + (lane >> 3);
  const int ch = lane & 7;
  const float4* xr = (const float4*)(x + (size_t)row * 128 + ch * 16);
  float4 V[4];
  float s = 0.f, ss = 0.f;
#pragma unroll
  for (int q = 0; q < 4; ++q) {
    V[q] = xr[q];
    s  += V[q].x + V[q].y + V[q].z + V[q].w;
    ss += V[q].x * V[q].x + V[q].y * V[q].y + V[q].z * V[q].z + V[q].w * V[q].w;
  }
#pragma unroll
  for (int o = 1; o < 8; o <<= 1) { s += __shfl_xor(s, o); ss += __shfl_xor(ss, o); }
  float mu  = s * 0.0078125f;
  float var = ss * 0.0078125f - mu * mu;
  float rs  = rsqrtf(var + 1e-5f);
  const float4* gp = (const float4*)(g + ch * 16);
  const float4* bp = (const float4*)(b + ch * 16);
  unsigned pk[8];
#pragma unroll
  for (int q = 0; q < 4; ++q) {
    float4 vv = V[q], gg = gp[q], bb = bp[q];
    pk[2 * q]     = pack2((vv.x - mu) * rs * gg.x + bb.x, (vv.y - mu) * rs * gg.y + bb.y);
    pk[2 * q + 1] = pack2((vv.z - mu) * rs * gg.z + bb.z, (vv.w - mu) * rs * gg.w + bb.w);
  }
  unsigned short* dst = xn + (size_t)row * 128 + ch * 16;
  *(uint4*)dst       = make_uint4(pk[0], pk[1], pk[2], pk[3]);
  *(uint4*)(dst + 8) = make_uint4(pk[4], pk[5], pk[6], pk[7]);
}

// ---------------- K2: masked+gated projection, both sides in one launch ----
// blockIdx.z selects side L (0) / R (1); per-block body is IDENTICAL to the
// proven two-launch k_proj — merging only removes the launch boundary so
// side-R blocks fill side-L's tail wave.
__global__ __launch_bounds__(256) void k_proj(
    const unsigned short* __restrict__ xn,
    const unsigned short* __restrict__ WlT, const float* __restrict__ bl,
    const unsigned short* __restrict__ WlgT, const float* __restrict__ blg,
    const unsigned short* __restrict__ WrT, const float* __restrict__ br,
    const unsigned short* __restrict__ WrgT, const float* __restrict__ brg,
    const int* __restrict__ mask,
    unsigned short* __restrict__ leftT, unsigned short* __restrict__ rightT) {
  const int side = blockIdx.z;
  const unsigned short* WpT = side ? WrT : WlT;
  const unsigned short* WgT = side ? WrgT : WlgT;
  const float* bp = side ? br : bl;
  const float* bg = side ? brg : blg;
  unsigned short* outb = side ? rightT : leftT;

  const int c  = blockIdx.y;
  const int k0 = blockIdx.x * 128;
  const int t = threadIdx.x, lane = t & 63, wid = t >> 6;
  const int wm = (wid >> 1) * 64, wn = (wid & 1) * 64;
  const int lr = lane & 15, lg = lane >> 4;
  __shared__ unsigned short sX[128 * 136];   // [k-local][d], padded rows
  __shared__ unsigned short sW[128 * 136];   // [h][d]

#pragma unroll
  for (int it = 0; it < 8; ++it) {
    int lin = it * 256 + t;
    int r = lin >> 4, ch = lin & 15;
    *(uint4*)&sX[r * 136 + ch * 8] =
        *(const uint4*)&xn[((size_t)(k0 + r) * NN + c) * 128 + ch * 8];
  }
#pragma unroll
  for (int it = 0; it < 8; ++it) {
    int lin = it * 256 + t;
    *(uint4*)&sW[(lin >> 4) * 136 + (lin & 15) * 8] = *(const uint4*)&WgT[lin * 8];
  }
  __syncthreads();

  f32x4 acc[4][4];
#pragma unroll
  for (int m = 0; m < 4; ++m)
#pragma unroll
    for (int n = 0; n < 4; ++n) { acc[m][n][0] = 0.f; acc[m][n][1] = 0.f; acc[m][n][2] = 0.f; acc[m][n][3] = 0.f; }

#pragma unroll
  for (int kk = 0; kk < 4; ++kk) {
    bf16x8 av[4], bv[4];
#pragma unroll
    for (int m = 0; m < 4; ++m)
      av[m] = *(const bf16x8*)&sW[(wm + m * 16 + lr) * 136 + kk * 32 + lg * 8];
#pragma unroll
    for (int n = 0; n < 4; ++n)
      bv[n] = *(const bf16x8*)&sX[(wn + n * 16 + lr) * 136 + kk * 32 + lg * 8];
#pragma unroll
    for (int m = 0; m < 4; ++m)
#pragma unroll
      for (int n = 0; n < 4; ++n)
        acc[m][n] = MFMA16(av[m], bv[n], acc[m][n], 0, 0, 0);
  }
  float sg[4][4][4];
#pragma unroll
  for (int m = 0; m < 4; ++m)
#pragma unroll
    for (int r = 0; r < 4; ++r) {
      int h = wm + m * 16 + lg * 4 + r;
      float bgv = bg[h];
#pragma unroll
      for (int n = 0; n < 4; ++n) sg[m][n][r] = sigm(acc[m][n][r] + bgv);
    }
  __syncthreads();
#pragma unroll
  for (int it = 0; it < 8; ++it) {
    int lin = it * 256 + t;
    *(uint4*)&sW[(lin >> 4) * 136 + (lin & 15) * 8] = *(const uint4*)&WpT[lin * 8];
  }
  __syncthreads();

#pragma unroll
  for (int m = 0; m < 4; ++m)
#pragma unroll
    for (int n = 0; n < 4; ++n) { acc[m][n][0] = 0.f; acc[m][n][1] = 0.f; acc[m][n][2] = 0.f; acc[m][n][3] = 0.f; }
#pragma unroll
  for (int kk = 0; kk < 4; ++kk) {
    bf16x8 av[4], bv[4];
#pragma unroll
    for (int m = 0; m < 4; ++m)
      av[m] = *(const bf16x8*)&sW[(wm + m * 16 + lr) * 136 + kk * 32 + lg * 8];
#pragma unroll
    for (int n = 0; n < 4; ++n)
      bv[n] = *(const bf16x8*)&sX[(wn + n * 16 + lr) * 136 + kk * 32 + lg * 8];
#pragma unroll
    for (int m = 0; m < 4; ++m)
#pragma unroll
      for (int n = 0; n < 4; ++n)
        acc[m][n] = MFMA16(av[m], bv[n], acc[m][n], 0, 0, 0);
  }

  const int maskc = mask[c];
  float mcol[4];
#pragma unroll
  for (int n = 0; n < 4; ++n)
    mcol[n] = (float)(maskc * mask[k0 + wn + n * 16 + lr]);
#pragma unroll
  for (int m = 0; m < 4; ++m)
#pragma unroll
    for (int r = 0; r < 4; ++r) {
      int h = wm + m * 16 + lg * 4 + r;
      float bpv = bp[h];
#pragma unroll
      for (int n = 0; n < 4; ++n) {
        float v = (acc[m][n][r] + bpv) * mcol[n] * sg[m][n][r];
        outb[(size_t)h * PP + (size_t)c * NN + k0 + wn + n * 16 + lr] = f2bf(v);
      }
    }
}

// ---------------- K4: einsum bkjd,bkid->bijd as 128 batched 512^3 GEMMs ----
// 256x256 tile per block, 512 threads = 8 waves (2x4), each 128x64.
// T14 async-STAGE prefetch: kb+1's global loads issued before kb's compute.
__global__ __launch_bounds__(512) void k_einsum(
    const unsigned short* __restrict__ rightT,
    const unsigned short* __restrict__ leftT,
    unsigned short* __restrict__ tmp) {
  const int bid = (blockIdx.x & 7) * 64 + (blockIdx.x >> 3);  // 512 = 8*64
  const int d = bid >> 2;
  const int i0 = ((bid >> 1) & 1) * 256, j0 = (bid & 1) * 256;
  const unsigned short* A = rightT + (size_t)d * PP;
  const unsigned short* B = leftT + (size_t)d * PP;
  const int t = threadIdx.x, lane = t & 63, wid = t >> 6;
  const int wm = (wid >> 2) * 128, wn = (wid & 3) * 64;
  const int lr = lane & 15, lg = lane >> 4;
  const int sr = t >> 3;                     // staging row 0..63 (+64*it)
  const int sc = (t & 7) * 8;                // staging col elem (16B chunks)
  __shared__ unsigned short sA[256 * 72];    // [i-local][k-local], padded
  __shared__ unsigned short sB[256 * 72];    // [j-local][k-local]

  f32x4 acc[8][4];
#pragma unroll
  for (int m = 0; m < 8; ++m)
#pragma unroll
    for (int n = 0; n < 4; ++n) { acc[m][n][0] = 0.f; acc[m][n][1] = 0.f; acc[m][n][2] = 0.f; acc[m][n][3] = 0.f; }

  // prologue: stage kb=0 directly
  uint4 pa0, pa1, pa2, pa3, pb0, pb1, pb2, pb3;
  pa0 = *(const uint4*)&A[(size_t)(i0 + sr)       * NN + sc];
  pa1 = *(const uint4*)&A[(size_t)(i0 + 64 + sr)  * NN + sc];
  pa2 = *(const uint4*)&A[(size_t)(i0 + 128 + sr) * NN + sc];
  pa3 = *(const uint4*)&A[(size_t)(i0 + 192 + sr) * NN + sc];
  pb0 = *(const uint4*)&B[(size_t)(j0 + sr)       * NN + sc];
  pb1 = *(const uint4*)&B[(size_t)(j0 + 64 + sr)  * NN + sc];
  pb2 = *(const uint4*)&B[(size_t)(j0 + 128 + sr) * NN + sc];
  pb3 = *(const uint4*)&B[(size_t)(j0 + 192 + sr) * NN + sc];
  *(uint4*)&sA[(sr)       * 72 + sc] = pa0;
  *(uint4*)&sA[(64 + sr)  * 72 + sc] = pa1;
  *(uint4*)&sA[(128 + sr) * 72 + sc] = pa2;
  *(uint4*)&sA[(192 + sr) * 72 + sc] = pa3;
  *(uint4*)&sB[(sr)       * 72 + sc] = pb0;
  *(uint4*)&sB[(64 + sr)  * 72 + sc] = pb1;
  *(uint4*)&sB[(128 + sr) * 72 + sc] = pb2;
  *(uint4*)&sB[(192 + sr) * 72 + sc] = pb3;
  __syncthreads();

  for (int kb = 0; kb < 8; ++kb) {
    if (kb < 7) {                            // issue kb+1 loads (in flight
      const int ko = (kb + 1) * 64 + sc;     //  across the compute below)
      pa0 = *(const uint4*)&A[(size_t)(i0 + sr)       * NN + ko];
      pa1 = *(const uint4*)&A[(size_t)(i0 + 64 + sr)  * NN + ko];
      pa2 = *(const uint4*)&A[(size_t)(i0 + 128 + sr) * NN + ko];
      pa3 = *(const uint4*)&A[(size_t)(i0 + 192 + sr) * NN + ko];
      pb0 = *(const uint4*)&B[(size_t)(j0 + sr)       * NN + ko];
      pb1 = *(const uint4*)&B[(size_t)(j0 + 64 + sr)  * NN + ko];
      pb2 = *(const uint4*)&B[(size_t)(j0 + 128 + sr) * NN + ko];
      pb3 = *(const uint4*)&B[(size_t)(j0 + 192 + sr) * NN + ko];
    }
#pragma unroll
    for (int kk = 0; kk < 2; ++kk) {
      bf16x8 bv[4];
#pragma unroll
      for (int n = 0; n < 4; ++n)
        bv[n] = *(const bf16x8*)&sB[(wn + n * 16 + lr) * 72 + kk * 32 + lg * 8];
#pragma unroll
      for (int m = 0; m < 8; ++m) {
        bf16x8 av = *(const bf16x8*)&sA[(wm + m * 16 + lr) * 72 + kk * 32 + lg * 8];
#pragma unroll
        for (int n = 0; n < 4; ++n)
          acc[m][n] = MFMA16(av, bv[n], acc[m][n], 0, 0, 0);
      }
    }
    __syncthreads();                         // everyone done reading kb
    if (kb < 7) {
      *(uint4*)&sA[(sr)       * 72 + sc] = pa0;
      *(uint4*)&sA[(64 + sr)  * 72 + sc] = pa1;
      *(uint4*)&sA[(128 + sr) * 72 + sc] = pa2;
      *(uint4*)&sA[(192 + sr) * 72 + sc] = pa3;
      *(uint4*)&sB[(sr)       * 72 + sc] = pb0;
      *(uint4*)&sB[(64 + sr)  * 72 + sc] = pb1;
      *(uint4*)&sB[(128 + sr) * 72 + sc] = pb2;
      *(uint4*)&sB[(192 + sr) * 72 + sc] = pb3;
    }
    __syncthreads();                         // kb+1 visible
  }

#pragma unroll
  for (int m = 0; m < 8; ++m)
#pragma unroll
    for (int r = 0; r < 4; ++r) {
      int row = wm + m * 16 + lg * 4 + r;
#pragma unroll
      for (int n = 0; n < 4; ++n) {
        int col = wn + n * 16 + lr;
        tmp[(size_t)d * PP + (size_t)(i0 + row) * NN + j0 + col] = f2bf(acc[m][n][r]);
      }
    }
}

// ---------------- K5: out-LN * sigmoid(xn@Wog+bog), @Wo + bo ---------------
// v3 (best measured: ~92us; floor of this structure per R10 falsification).
__global__ __launch_bounds__(256, 2) void k_final(
    const unsigned short* __restrict__ xn,
    const unsigned short* __restrict__ WogT, const float* __restrict__ bog,
    const unsigned short* __restrict__ WoT, const float* __restrict__ bo,
    const unsigned short* __restrict__ tmp,
    const float* __restrict__ og, const float* __restrict__ ob,
    float* __restrict__ out) {
  const int p0 = blockIdx.x * 128;
  const int t = threadIdx.x, lane = t & 63, wid = t >> 6;
  const int wm = (wid >> 1) * 64, wn = (wid & 1) * 64;
  const int lr = lane & 15, lg = lane >> 4;
  __shared__ unsigned short sT[128 * 136];   // tmp tile, [p][h] swizzled
  __shared__ unsigned short sSig[128 * 136]; // sigmoid gate, [p][h] swizzled
  __shared__ float muL[128], rsL[128];

  // ---- stage sT: per thread 8 coalesced u32 loads (2p x 8h) -> 2x b128
  {
    const int pb = 2 * lane;
#pragma unroll
    for (int q = 0; q < 4; ++q) {
      int h0 = (q * 4 + wid) * 8;
      unsigned a[8];
#pragma unroll
      for (int e = 0; e < 8; ++e)
        a[e] = *(const unsigned*)&tmp[(size_t)(h0 + e) * PP + p0 + pb];
      bf16x8 y0, y1;
#pragma unroll
      for (int e = 0; e < 8; ++e) {
        y0[e] = (short)(a[e] & 0xffffu);
        y1[e] = (short)(a[e] >> 16);
      }
      *(bf16x8*)&sT[sidx(pb, h0)]     = y0;
      *(bf16x8*)&sT[sidx(pb + 1, h0)] = y1;
    }
  }

  // ---- GEMM1: sig pre-activation C[p,h] = xn @ Wog (fragments from global)
  f32x4 acc[4][4];
#pragma unroll
  for (int m = 0; m < 4; ++m)
#pragma unroll
    for (int n = 0; n < 4; ++n) { acc[m][n][0] = 0.f; acc[m][n][1] = 0.f; acc[m][n][2] = 0.f; acc[m][n][3] = 0.f; }
#pragma unroll
  for (int kk = 0; kk < 4; ++kk) {
    bf16x8 av[4], bv[4];
#pragma unroll
    for (int m = 0; m < 4; ++m)
      av[m] = *(const bf16x8*)&xn[(size_t)(p0 + wm + m * 16 + lr) * 128 + kk * 32 + lg * 8];
#pragma unroll
    for (int n = 0; n < 4; ++n)
      bv[n] = *(const bf16x8*)&WogT[(wn + n * 16 + lr) * 128 + kk * 32 + lg * 8];
#pragma unroll
    for (int m = 0; m < 4; ++m)
#pragma unroll
      for (int n = 0; n < 4; ++n)
        acc[m][n] = MFMA16(av[m], bv[n], acc[m][n], 0, 0, 0);
  }
  float bogv[4];
#pragma unroll
  for (int n = 0; n < 4; ++n) bogv[n] = bog[wn + n * 16 + lr];
#pragma unroll
  for (int m = 0; m < 4; ++m)
#pragma unroll
    for (int r = 0; r < 4; ++r) {
      int p = wm + m * 16 + lg * 4 + r;
#pragma unroll
      for (int n = 0; n < 4; ++n)
        sSig[sidx(p, wn + n * 16 + lr)] = f2bf(sigm(acc[m][n][r] + bogv[n]));
    }
  __syncthreads();

  // ---- LN stats from sT: 2 threads per row
  {
    int p = t >> 1, half = t & 1;
    float s = 0.f, ss = 0.f;
#pragma unroll
    for (int c = 0; c < 8; ++c) {
      bf16x8 v = *(const bf16x8*)&sT[sidx(p, half * 64 + c * 8)];
#pragma unroll
      for (int e = 0; e < 8; ++e) {
        float f = bf2f((unsigned short)v[e]);
        s += f; ss += f * f;
      }
    }
    s += __shfl_xor(s, 1); ss += __shfl_xor(ss, 1);
    if (half == 0) {
      float mu = s * 0.0078125f;
      float var = ss * 0.0078125f - mu * mu;
      muL[p] = mu;
      rsL[p] = rsqrtf(var + 1e-5f);
    }
  }
  __syncthreads();

  // ---- GEMM2: out[p,e] = y @ Wo, y built on the fly from sT/sSig/LN
#pragma unroll
  for (int m = 0; m < 4; ++m)
#pragma unroll
    for (int n = 0; n < 4; ++n) { acc[m][n][0] = 0.f; acc[m][n][1] = 0.f; acc[m][n][2] = 0.f; acc[m][n][3] = 0.f; }
  float muR[4], rsR[4];
#pragma unroll
  for (int m = 0; m < 4; ++m) {
    int p = wm + m * 16 + lr;
    muR[m] = muL[p]; rsR[m] = rsL[p];
  }
#pragma unroll
  for (int kk = 0; kk < 4; ++kk) {
    const int h0 = kk * 32 + lg * 8;
    float ogv[8], obv[8];
    *(float4*)&ogv[0] = *(const float4*)&og[h0];
    *(float4*)&ogv[4] = *(const float4*)&og[h0 + 4];
    *(float4*)&obv[0] = *(const float4*)&ob[h0];
    *(float4*)&obv[4] = *(const float4*)&ob[h0 + 4];
    bf16x8 av[4], bv[4];
#pragma unroll
    for (int m = 0; m < 4; ++m) {
      int p = wm + m * 16 + lr;
      float mu = muR[m], rr = rsR[m];
      bf16x8 tv = *(const bf16x8*)&sT[sidx(p, h0)];
      bf16x8 gv = *(const bf16x8*)&sSig[sidx(p, h0)];
      bf16x8 y;
#pragma unroll
      for (int e = 0; e < 8; ++e) {
        float tf = bf2f((unsigned short)tv[e]);
        float yf = ((tf - mu) * rr * ogv[e] + obv[e]) * bf2f((unsigned short)gv[e]);
        y[e] = (short)f2bf(yf);
      }
      av[m] = y;
    }
#pragma unroll
    for (int n = 0; n < 4; ++n)
      bv[n] = *(const bf16x8*)&WoT[(wn + n * 16 + lr) * 128 + h0];
#pragma unroll
    for (int m = 0; m < 4; ++m)
#pragma unroll
      for (int n = 0; n < 4; ++n)
        acc[m][n] = MFMA16(av[m], bv[n], acc[m][n], 0, 0, 0);
  }

  float bov[4];
#pragma unroll
  for (int n = 0; n < 4; ++n) bov[n] = bo[wn + n * 16 + lr];
#pragma unroll
  for (int m = 0; m < 4; ++m)
#pragma unroll
    for (int r = 0; r < 4; ++r) {
      int p = wm + m * 16 + lg * 4 + r;
#pragma unroll
      for (int n = 0; n < 4; ++n)
        out[(size_t)(p0 + p) * 128 + wn + n * 16 + lr] = acc[m][n][r] + bov[n];
    }
}

extern "C" void kernel_launch(void* const* d_in, const int* in_sizes, int n_in,
                              void* d_out, int out_size, void* d_ws, size_t ws_size,
                              hipStream_t stream) {
  (void)in_sizes; (void)n_in; (void)out_size;
  const float* x    = (const float*)d_in[0];
  const int*   msk  = (const int*)d_in[1];
  const float* ln_g = (const float*)d_in[2];
  const float* ln_b = (const float*)d_in[3];
  const float* Wl   = (const float*)d_in[4];
  const float* bl   = (const float*)d_in[5];
  const float* Wr   = (const float*)d_in[6];
  const float* br   = (const float*)d_in[7];
  const float* Wlg  = (const float*)d_in[8];
  const float* blg  = (const float*)d_in[9];
  const float* Wrg  = (const float*)d_in[10];
  const float* brg  = (const float*)d_in[11];
  const float* Wog  = (const float*)d_in[12];
  const float* bog  = (const float*)d_in[13];
  const float* olng = (const float*)d_in[14];
  const float* olnb = (const float*)d_in[15];
  const float* Wo   = (const float*)d_in[16];
  const float* bo   = (const float*)d_in[17];
  float* out = (float*)d_out;

  const size_t need = (1ull << 20) + 4ull * (1ull << 26);
  if (ws_size < need) return;
  char* ws = (char*)d_ws;
  unsigned short* wT    = (unsigned short*)ws;
  unsigned short* xn    = (unsigned short*)(ws + (1ull << 20));
  unsigned short* leftT = (unsigned short*)(ws + (1ull << 20) + (1ull << 26));
  unsigned short* rightT= (unsigned short*)(ws + (1ull << 20) + (2ull << 26));
  unsigned short* tmp   = (unsigned short*)(ws + (1ull << 20) + (3ull << 26));

  hipLaunchKernelGGL(k_prep, dim3(6), dim3(256), 0, stream, Wl, Wr, Wlg, Wrg, Wog, Wo, wT);
  hipLaunchKernelGGL(k_ln, dim3(PP / 32), dim3(256), 0, stream, x, ln_g, ln_b, xn);
  hipLaunchKernelGGL(k_proj, dim3(4, NN, 2), dim3(256), 0, stream,
                     xn,
                     wT + 0 * 16384, bl, wT + 2 * 16384, blg,
                     wT + 1 * 16384, br, wT + 3 * 16384, brg,
                     msk, leftT, rightT);
  hipLaunchKernelGGL(k_einsum, dim3(512), dim3(512), 0, stream, rightT, leftT, tmp);
  hipLaunchKernelGGL(k_final, dim3(PP / 128), dim3(256), 0, stream,
                     xn, wT + 4 * 16384, bog, wT + 5 * 16384, bo, tmp, olng, olnb, out);
}

// Round 19
// 255.774 us; speedup vs baseline: 1.2598x; 1.0275x over previous
//
#include <hip/hip_runtime.h>
#include <stdint.h>

#define NN 512
#define PP (NN * NN)   // 262144 positions

typedef __attribute__((ext_vector_type(8))) short bf16x8;
typedef __attribute__((ext_vector_type(4))) float f32x4;

#define MFMA16 __builtin_amdgcn_mfma_f32_16x16x32_bf16

__device__ __forceinline__ unsigned short f2bf(float f) {
  unsigned u = __float_as_uint(f);
  u += 0x7fffu + ((u >> 16) & 1u);   // round-to-nearest-even
  return (unsigned short)(u >> 16);
}
__device__ __forceinline__ float bf2f(unsigned short s) {
  return __uint_as_float(((unsigned)s) << 16);
}
__device__ __forceinline__ unsigned pack2(float a, float b) {
  return (unsigned)f2bf(a) | ((unsigned)f2bf(b) << 16);
}
__device__ __forceinline__ float sigm(float t) { return 1.0f / (1.0f + __expf(-t)); }

// swizzled LDS index for [p][h] tiles, row stride 136 ushorts (272B).
// XOR of p bits 3-5 into h bits 3-5; keeps 8-aligned h-chunks 16B-aligned.
__device__ __forceinline__ int sidx(int p, int h) {
  return p * 136 + (h ^ (((p >> 3) & 7) << 3));
}

// ---------------- K1: fused {weight prep (6 blocks)} + {LayerNorm} ---------
// Blocks >= PP/32 transpose+cast one 128x128 weight each (independent of the
// LN work; merged to remove one launch boundary — same mechanism as the
// proj-side merge, R18 +7us).  Blocks < PP/32 run the proven LN body.
__global__ __launch_bounds__(256) void k_prep_ln(
    const float* __restrict__ x, const float* __restrict__ g,
    const float* __restrict__ b, unsigned short* __restrict__ xn,
    const float* __restrict__ w0, const float* __restrict__ w1,
    const float* __restrict__ w2, const float* __restrict__ w3,
    const float* __restrict__ w4, const float* __restrict__ w5,
    unsigned short* __restrict__ outw) {
  if (blockIdx.x >= PP / 32) {               // ---- prep path (6 blocks)
    const int m = blockIdx.x - PP / 32;
    const float* src;
    switch (m) {
      case 0: src = w0; break; case 1: src = w1; break; case 2: src = w2; break;
      case 3: src = w3; break; case 4: src = w4; break; default: src = w5; break;
    }
    unsigned short* o = outw + m * 16384;
    for (int idx = threadIdx.x; idx < 16384; idx += 256) {
      int r = idx >> 7, c = idx & 127;
      o[idx] = f2bf(src[c * 128 + r]);
    }
    return;
  }
  // ---- LN path (PP/32 blocks), unchanged body
  const int lane = threadIdx.x & 63, wid = threadIdx.x >> 6;
  const int row = blockIdx.x * 32 + wid * 8 + (lane >> 3);
  const int ch = lane & 7;
  const float4* xr = (const float4*)(x + (size_t)row * 128 + ch * 16);
  float4 V[4];
  float s = 0.f, ss = 0.f;
#pragma unroll
  for (int q = 0; q < 4; ++q) {
    V[q] = xr[q];
    s  += V[q].x + V[q].y + V[q].z + V[q].w;
    ss += V[q].x * V[q].x + V[q].y * V[q].y + V[q].z * V[q].z + V[q].w * V[q].w;
  }
#pragma unroll
  for (int o = 1; o < 8; o <<= 1) { s += __shfl_xor(s, o); ss += __shfl_xor(ss, o); }
  float mu  = s * 0.0078125f;
  float var = ss * 0.0078125f - mu * mu;
  float rs  = rsqrtf(var + 1e-5f);
  const float4* gp = (const float4*)(g + ch * 16);
  const float4* bp = (const float4*)(b + ch * 16);
  unsigned pk[8];
#pragma unroll
  for (int q = 0; q < 4; ++q) {
    float4 vv = V[q], gg = gp[q], bb = bp[q];
    pk[2 * q]     = pack2((vv.x - mu) * rs * gg.x + bb.x, (vv.y - mu) * rs * gg.y + bb.y);
    pk[2 * q + 1] = pack2((vv.z - mu) * rs * gg.z + bb.z, (vv.w - mu) * rs * gg.w + bb.w);
  }
  unsigned short* dst = xn + (size_t)row * 128 + ch * 16;
  *(uint4*)dst       = make_uint4(pk[0], pk[1], pk[2], pk[3]);
  *(uint4*)(dst + 8) = make_uint4(pk[4], pk[5], pk[6], pk[7]);
}

// ---------------- K2: masked+gated projection, both sides in one launch ----
// blockIdx.z selects side L (0) / R (1); per-block body is IDENTICAL to the
// proven two-launch k_proj — merging only removes the launch boundary so
// side-R blocks fill side-L's tail wave.  (R18: -7.3us, counters unchanged.)
__global__ __launch_bounds__(256) void k_proj(
    const unsigned short* __restrict__ xn,
    const unsigned short* __restrict__ WlT, const float* __restrict__ bl,
    const unsigned short* __restrict__ WlgT, const float* __restrict__ blg,
    const unsigned short* __restrict__ WrT, const float* __restrict__ br,
    const unsigned short* __restrict__ WrgT, const float* __restrict__ brg,
    const int* __restrict__ mask,
    unsigned short* __restrict__ leftT, unsigned short* __restrict__ rightT) {
  const int side = blockIdx.z;
  const unsigned short* WpT = side ? WrT : WlT;
  const unsigned short* WgT = side ? WrgT : WlgT;
  const float* bp = side ? br : bl;
  const float* bg = side ? brg : blg;
  unsigned short* outb = side ? rightT : leftT;

  const int c  = blockIdx.y;
  const int k0 = blockIdx.x * 128;
  const int t = threadIdx.x, lane = t & 63, wid = t >> 6;
  const int wm = (wid >> 1) * 64, wn = (wid & 1) * 64;
  const int lr = lane & 15, lg = lane >> 4;
  __shared__ unsigned short sX[128 * 136];   // [k-local][d], padded rows
  __shared__ unsigned short sW[128 * 136];   // [h][d]

#pragma unroll
  for (int it = 0; it < 8; ++it) {
    int lin = it * 256 + t;
    int r = lin >> 4, ch = lin & 15;
    *(uint4*)&sX[r * 136 + ch * 8] =
        *(const uint4*)&xn[((size_t)(k0 + r) * NN + c) * 128 + ch * 8];
  }
#pragma unroll
  for (int it = 0; it < 8; ++it) {
    int lin = it * 256 + t;
    *(uint4*)&sW[(lin >> 4) * 136 + (lin & 15) * 8] = *(const uint4*)&WgT[lin * 8];
  }
  __syncthreads();

  f32x4 acc[4][4];
#pragma unroll
  for (int m = 0; m < 4; ++m)
#pragma unroll
    for (int n = 0; n < 4; ++n) { acc[m][n][0] = 0.f; acc[m][n][1] = 0.f; acc[m][n][2] = 0.f; acc[m][n][3] = 0.f; }

#pragma unroll
  for (int kk = 0; kk < 4; ++kk) {
    bf16x8 av[4], bv[4];
#pragma unroll
    for (int m = 0; m < 4; ++m)
      av[m] = *(const bf16x8*)&sW[(wm + m * 16 + lr) * 136 + kk * 32 + lg * 8];
#pragma unroll
    for (int n = 0; n < 4; ++n)
      bv[n] = *(const bf16x8*)&sX[(wn + n * 16 + lr) * 136 + kk * 32 + lg * 8];
#pragma unroll
    for (int m = 0; m < 4; ++m)
#pragma unroll
      for (int n = 0; n < 4; ++n)
        acc[m][n] = MFMA16(av[m], bv[n], acc[m][n], 0, 0, 0);
  }
  float sg[4][4][4];
#pragma unroll
  for (int m = 0; m < 4; ++m)
#pragma unroll
    for (int r = 0; r < 4; ++r) {
      int h = wm + m * 16 + lg * 4 + r;
      float bgv = bg[h];
#pragma unroll
      for (int n = 0; n < 4; ++n) sg[m][n][r] = sigm(acc[m][n][r] + bgv);
    }
  __syncthreads();
#pragma unroll
  for (int it = 0; it < 8; ++it) {
    int lin = it * 256 + t;
    *(uint4*)&sW[(lin >> 4) * 136 + (lin & 15) * 8] = *(const uint4*)&WpT[lin * 8];
  }
  __syncthreads();

#pragma unroll
  for (int m = 0; m < 4; ++m)
#pragma unroll
    for (int n = 0; n < 4; ++n) { acc[m][n][0] = 0.f; acc[m][n][1] = 0.f; acc[m][n][2] = 0.f; acc[m][n][3] = 0.f; }
#pragma unroll
  for (int kk = 0; kk < 4; ++kk) {
    bf16x8 av[4], bv[4];
#pragma unroll
    for (int m = 0; m < 4; ++m)
      av[m] = *(const bf16x8*)&sW[(wm + m * 16 + lr) * 136 + kk * 32 + lg * 8];
#pragma unroll
    for (int n = 0; n < 4; ++n)
      bv[n] = *(const bf16x8*)&sX[(wn + n * 16 + lr) * 136 + kk * 32 + lg * 8];
#pragma unroll
    for (int m = 0; m < 4; ++m)
#pragma unroll
      for (int n = 0; n < 4; ++n)
        acc[m][n] = MFMA16(av[m], bv[n], acc[m][n], 0, 0, 0);
  }

  const int maskc = mask[c];
  float mcol[4];
#pragma unroll
  for (int n = 0; n < 4; ++n)
    mcol[n] = (float)(maskc * mask[k0 + wn + n * 16 + lr]);
#pragma unroll
  for (int m = 0; m < 4; ++m)
#pragma unroll
    for (int r = 0; r < 4; ++r) {
      int h = wm + m * 16 + lg * 4 + r;
      float bpv = bp[h];
#pragma unroll
      for (int n = 0; n < 4; ++n) {
        float v = (acc[m][n][r] + bpv) * mcol[n] * sg[m][n][r];
        outb[(size_t)h * PP + (size_t)c * NN + k0 + wn + n * 16 + lr] = f2bf(v);
      }
    }
}

// ---------------- K4: einsum bkjd,bkid->bijd as 128 batched 512^3 GEMMs ----
// 256x256 tile per block, 512 threads = 8 waves (2x4), each 128x64.
// T14 async-STAGE prefetch: kb+1's global loads issued before kb's compute.
__global__ __launch_bounds__(512) void k_einsum(
    const unsigned short* __restrict__ rightT,
    const unsigned short* __restrict__ leftT,
    unsigned short* __restrict__ tmp) {
  const int bid = (blockIdx.x & 7) * 64 + (blockIdx.x >> 3);  // 512 = 8*64
  const int d = bid >> 2;
  const int i0 = ((bid >> 1) & 1) * 256, j0 = (bid & 1) * 256;
  const unsigned short* A = rightT + (size_t)d * PP;
  const unsigned short* B = leftT + (size_t)d * PP;
  const int t = threadIdx.x, lane = t & 63, wid = t >> 6;
  const int wm = (wid >> 2) * 128, wn = (wid & 3) * 64;
  const int lr = lane & 15, lg = lane >> 4;
  const int sr = t >> 3;                     // staging row 0..63 (+64*it)
  const int sc = (t & 7) * 8;                // staging col elem (16B chunks)
  __shared__ unsigned short sA[256 * 72];    // [i-local][k-local], padded
  __shared__ unsigned short sB[256 * 72];    // [j-local][k-local]

  f32x4 acc[8][4];
#pragma unroll
  for (int m = 0; m < 8; ++m)
#pragma unroll
    for (int n = 0; n < 4; ++n) { acc[m][n][0] = 0.f; acc[m][n][1] = 0.f; acc[m][n][2] = 0.f; acc[m][n][3] = 0.f; }

  // prologue: stage kb=0 directly
  uint4 pa0, pa1, pa2, pa3, pb0, pb1, pb2, pb3;
  pa0 = *(const uint4*)&A[(size_t)(i0 + sr)       * NN + sc];
  pa1 = *(const uint4*)&A[(size_t)(i0 + 64 + sr)  * NN + sc];
  pa2 = *(const uint4*)&A[(size_t)(i0 + 128 + sr) * NN + sc];
  pa3 = *(const uint4*)&A[(size_t)(i0 + 192 + sr) * NN + sc];
  pb0 = *(const uint4*)&B[(size_t)(j0 + sr)       * NN + sc];
  pb1 = *(const uint4*)&B[(size_t)(j0 + 64 + sr)  * NN + sc];
  pb2 = *(const uint4*)&B[(size_t)(j0 + 128 + sr) * NN + sc];
  pb3 = *(const uint4*)&B[(size_t)(j0 + 192 + sr) * NN + sc];
  *(uint4*)&sA[(sr)       * 72 + sc] = pa0;
  *(uint4*)&sA[(64 + sr)  * 72 + sc] = pa1;
  *(uint4*)&sA[(128 + sr) * 72 + sc] = pa2;
  *(uint4*)&sA[(192 + sr) * 72 + sc] = pa3;
  *(uint4*)&sB[(sr)       * 72 + sc] = pb0;
  *(uint4*)&sB[(64 + sr)  * 72 + sc] = pb1;
  *(uint4*)&sB[(128 + sr) * 72 + sc] = pb2;
  *(uint4*)&sB[(192 + sr) * 72 + sc] = pb3;
  __syncthreads();

  for (int kb = 0; kb < 8; ++kb) {
    if (kb < 7) {                            // issue kb+1 loads (in flight
      const int ko = (kb + 1) * 64 + sc;     //  across the compute below)
      pa0 = *(const uint4*)&A[(size_t)(i0 + sr)       * NN + ko];
      pa1 = *(const uint4*)&A[(size_t)(i0 + 64 + sr)  * NN + ko];
      pa2 = *(const uint4*)&A[(size_t)(i0 + 128 + sr) * NN + ko];
      pa3 = *(const uint4*)&A[(size_t)(i0 + 192 + sr) * NN + ko];
      pb0 = *(const uint4*)&B[(size_t)(j0 + sr)       * NN + ko];
      pb1 = *(const uint4*)&B[(size_t)(j0 + 64 + sr)  * NN + ko];
      pb2 = *(const uint4*)&B[(size_t)(j0 + 128 + sr) * NN + ko];
      pb3 = *(const uint4*)&B[(size_t)(j0 + 192 + sr) * NN + ko];
    }
#pragma unroll
    for (int kk = 0; kk < 2; ++kk) {
      bf16x8 bv[4];
#pragma unroll
      for (int n = 0; n < 4; ++n)
        bv[n] = *(const bf16x8*)&sB[(wn + n * 16 + lr) * 72 + kk * 32 + lg * 8];
#pragma unroll
      for (int m = 0; m < 8; ++m) {
        bf16x8 av = *(const bf16x8*)&sA[(wm + m * 16 + lr) * 72 + kk * 32 + lg * 8];
#pragma unroll
        for (int n = 0; n < 4; ++n)
          acc[m][n] = MFMA16(av, bv[n], acc[m][n], 0, 0, 0);
      }
    }
    __syncthreads();                         // everyone done reading kb
    if (kb < 7) {
      *(uint4*)&sA[(sr)       * 72 + sc] = pa0;
      *(uint4*)&sA[(64 + sr)  * 72 + sc] = pa1;
      *(uint4*)&sA[(128 + sr) * 72 + sc] = pa2;
      *(uint4*)&sA[(192 + sr) * 72 + sc] = pa3;
      *(uint4*)&sB[(sr)       * 72 + sc] = pb0;
      *(uint4*)&sB[(64 + sr)  * 72 + sc] = pb1;
      *(uint4*)&sB[(128 + sr) * 72 + sc] = pb2;
      *(uint4*)&sB[(192 + sr) * 72 + sc] = pb3;
    }
    __syncthreads();                         // kb+1 visible
  }

#pragma unroll
  for (int m = 0; m < 8; ++m)
#pragma unroll
    for (int r = 0; r < 4; ++r) {
      int row = wm + m * 16 + lg * 4 + r;
#pragma unroll
      for (int n = 0; n < 4; ++n) {
        int col = wn + n * 16 + lr;
        tmp[(size_t)d * PP + (size_t)(i0 + row) * NN + j0 + col] = f2bf(acc[m][n][r]);
      }
    }
}

// ---------------- K5: out-LN * sigmoid(xn@Wog+bog), @Wo + bo ---------------
// v3 (best measured: ~92us; floor of this structure per R10 falsification).
__global__ __launch_bounds__(256, 2) void k_final(
    const unsigned short* __restrict__ xn,
    const unsigned short* __restrict__ WogT, const float* __restrict__ bog,
    const unsigned short* __restrict__ WoT, const float* __restrict__ bo,
    const unsigned short* __restrict__ tmp,
    const float* __restrict__ og, const float* __restrict__ ob,
    float* __restrict__ out) {
  const int p0 = blockIdx.x * 128;
  const int t = threadIdx.x, lane = t & 63, wid = t >> 6;
  const int wm = (wid >> 1) * 64, wn = (wid & 1) * 64;
  const int lr = lane & 15, lg = lane >> 4;
  __shared__ unsigned short sT[128 * 136];   // tmp tile, [p][h] swizzled
  __shared__ unsigned short sSig[128 * 136]; // sigmoid gate, [p][h] swizzled
  __shared__ float muL[128], rsL[128];

  // ---- stage sT: per thread 8 coalesced u32 loads (2p x 8h) -> 2x b128
  {
    const int pb = 2 * lane;
#pragma unroll
    for (int q = 0; q < 4; ++q) {
      int h0 = (q * 4 + wid) * 8;
      unsigned a[8];
#pragma unroll
      for (int e = 0; e < 8; ++e)
        a[e] = *(const unsigned*)&tmp[(size_t)(h0 + e) * PP + p0 + pb];
      bf16x8 y0, y1;
#pragma unroll
      for (int e = 0; e < 8; ++e) {
        y0[e] = (short)(a[e] & 0xffffu);
        y1[e] = (short)(a[e] >> 16);
      }
      *(bf16x8*)&sT[sidx(pb, h0)]     = y0;
      *(bf16x8*)&sT[sidx(pb + 1, h0)] = y1;
    }
  }

  // ---- GEMM1: sig pre-activation C[p,h] = xn @ Wog (fragments from global)
  f32x4 acc[4][4];
#pragma unroll
  for (int m = 0; m < 4; ++m)
#pragma unroll
    for (int n = 0; n < 4; ++n) { acc[m][n][0] = 0.f; acc[m][n][1] = 0.f; acc[m][n][2] = 0.f; acc[m][n][3] = 0.f; }
#pragma unroll
  for (int kk = 0; kk < 4; ++kk) {
    bf16x8 av[4], bv[4];
#pragma unroll
    for (int m = 0; m < 4; ++m)
      av[m] = *(const bf16x8*)&xn[(size_t)(p0 + wm + m * 16 + lr) * 128 + kk * 32 + lg * 8];
#pragma unroll
    for (int n = 0; n < 4; ++n)
      bv[n] = *(const bf16x8*)&WogT[(wn + n * 16 + lr) * 128 + kk * 32 + lg * 8];
#pragma unroll
    for (int m = 0; m < 4; ++m)
#pragma unroll
      for (int n = 0; n < 4; ++n)
        acc[m][n] = MFMA16(av[m], bv[n], acc[m][n], 0, 0, 0);
  }
  float bogv[4];
#pragma unroll
  for (int n = 0; n < 4; ++n) bogv[n] = bog[wn + n * 16 + lr];
#pragma unroll
  for (int m = 0; m < 4; ++m)
#pragma unroll
    for (int r = 0; r < 4; ++r) {
      int p = wm + m * 16 + lg * 4 + r;
#pragma unroll
      for (int n = 0; n < 4; ++n)
        sSig[sidx(p, wn + n * 16 + lr)] = f2bf(sigm(acc[m][n][r] + bogv[n]));
    }
  __syncthreads();

  // ---- LN stats from sT: 2 threads per row
  {
    int p = t >> 1, half = t & 1;
    float s = 0.f, ss = 0.f;
#pragma unroll
    for (int c = 0; c < 8; ++c) {
      bf16x8 v = *(const bf16x8*)&sT[sidx(p, half * 64 + c * 8)];
#pragma unroll
      for (int e = 0; e < 8; ++e) {
        float f = bf2f((unsigned short)v[e]);
        s += f; ss += f * f;
      }
    }
    s += __shfl_xor(s, 1); ss += __shfl_xor(ss, 1);
    if (half == 0) {
      float mu = s * 0.0078125f;
      float var = ss * 0.0078125f - mu * mu;
      muL[p] = mu;
      rsL[p] = rsqrtf(var + 1e-5f);
    }
  }
  __syncthreads();

  // ---- GEMM2: out[p,e] = y @ Wo, y built on the fly from sT/sSig/LN
#pragma unroll
  for (int m = 0; m < 4; ++m)
#pragma unroll
    for (int n = 0; n < 4; ++n) { acc[m][n][0] = 0.f; acc[m][n][1] = 0.f; acc[m][n][2] = 0.f; acc[m][n][3] = 0.f; }
  float muR[4], rsR[4];
#pragma unroll
  for (int m = 0; m < 4; ++m) {
    int p = wm + m * 16 + lr;
    muR[m] = muL[p]; rsR[m] = rsL[p];
  }
#pragma unroll
  for (int kk = 0; kk < 4; ++kk) {
    const int h0 = kk * 32 + lg * 8;
    float ogv[8], obv[8];
    *(float4*)&ogv[0] = *(const float4*)&og[h0];
    *(float4*)&ogv[4] = *(const float4*)&og[h0 + 4];
    *(float4*)&obv[0] = *(const float4*)&ob[h0];
    *(float4*)&obv[4] = *(const float4*)&ob[h0 + 4];
    bf16x8 av[4], bv[4];
#pragma unroll
    for (int m = 0; m < 4; ++m) {
      int p = wm + m * 16 + lr;
      float mu = muR[m], rr = rsR[m];
      bf16x8 tv = *(const bf16x8*)&sT[sidx(p, h0)];
      bf16x8 gv = *(const bf16x8*)&sSig[sidx(p, h0)];
      bf16x8 y;
#pragma unroll
      for (int e = 0; e < 8; ++e) {
        float tf = bf2f((unsigned short)tv[e]);
        float yf = ((tf - mu) * rr * ogv[e] + obv[e]) * bf2f((unsigned short)gv[e]);
        y[e] = (short)f2bf(yf);
      }
      av[m] = y;
    }
#pragma unroll
    for (int n = 0; n < 4; ++n)
      bv[n] = *(const bf16x8*)&WoT[(wn + n * 16 + lr) * 128 + h0];
#pragma unroll
    for (int m = 0; m < 4; ++m)
#pragma unroll
      for (int n = 0; n < 4; ++n)
        acc[m][n] = MFMA16(av[m], bv[n], acc[m][n], 0, 0, 0);
  }

  float bov[4];
#pragma unroll
  for (int n = 0; n < 4; ++n) bov[n] = bo[wn + n * 16 + lr];
#pragma unroll
  for (int m = 0; m < 4; ++m)
#pragma unroll
    for (int r = 0; r < 4; ++r) {
      int p = wm + m * 16 + lg * 4 + r;
#pragma unroll
      for (int n = 0; n < 4; ++n)
        out[(size_t)(p0 + p) * 128 + wn + n * 16 + lr] = acc[m][n][r] + bov[n];
    }
}

extern "C" void kernel_launch(void* const* d_in, const int* in_sizes, int n_in,
                              void* d_out, int out_size, void* d_ws, size_t ws_size,
                              hipStream_t stream) {
  (void)in_sizes; (void)n_in; (void)out_size;
  const float* x    = (const float*)d_in[0];
  const int*   msk  = (const int*)d_in[1];
  const float* ln_g = (const float*)d_in[2];
  const float* ln_b = (const float*)d_in[3];
  const float* Wl   = (const float*)d_in[4];
  const float* bl   = (const float*)d_in[5];
  const float* Wr   = (const float*)d_in[6];
  const float* br   = (const float*)d_in[7];
  const float* Wlg  = (const float*)d_in[8];
  const float* blg  = (const float*)d_in[9];
  const float* Wrg  = (const float*)d_in[10];
  const float* brg  = (const float*)d_in[11];
  const float* Wog  = (const float*)d_in[12];
  const float* bog  = (const float*)d_in[13];
  const float* olng = (const float*)d_in[14];
  const float* olnb = (const float*)d_in[15];
  const float* Wo   = (const float*)d_in[16];
  const float* bo   = (const float*)d_in[17];
  float* out = (float*)d_out;

  const size_t need = (1ull << 20) + 4ull * (1ull << 26);
  if (ws_size < need) return;
  char* ws = (char*)d_ws;
  unsigned short* wT    = (unsigned short*)ws;
  unsigned short* xn    = (unsigned short*)(ws + (1ull << 20));
  unsigned short* leftT = (unsigned short*)(ws + (1ull << 20) + (1ull << 26));
  unsigned short* rightT= (unsigned short*)(ws + (1ull << 20) + (2ull << 26));
  unsigned short* tmp   = (unsigned short*)(ws + (1ull << 20) + (3ull << 26));

  hipLaunchKernelGGL(k_prep_ln, dim3(PP / 32 + 6), dim3(256), 0, stream,
                     x, ln_g, ln_b, xn, Wl, Wr, Wlg, Wrg, Wog, Wo, wT);
  hipLaunchKernelGGL(k_proj, dim3(4, NN, 2), dim3(256), 0, stream,
                     xn,
                     wT + 0 * 16384, bl, wT + 2 * 16384, blg,
                     wT + 1 * 16384, br, wT + 3 * 16384, brg,
                     msk, leftT, rightT);
  hipLaunchKernelGGL(k_einsum, dim3(512), dim3(512), 0, stream, rightT, leftT, tmp);
  hipLaunchKernelGGL(k_final, dim3(PP / 128), dim3(256), 0, stream,
                     xn, wT + 4 * 16384, bog, wT + 5 * 16384, bo, tmp, olng, olnb, out);
}